// Round 8
// baseline (3535.918 us; speedup 1.0000x reference)
//
#include <hip/hip_runtime.h>
#include <hip/hip_bf16.h>
#include <float.h>

typedef unsigned long long u64;

// ---------- exact-rounding helpers (match numpy fp32, no FMA contraction) ----------
static __device__ __forceinline__ float d2_rn(float ax, float ay, float az,
                                              float bx, float by, float bz) {
  float dx = __fsub_rn(ax, bx), dy = __fsub_rn(ay, by), dz = __fsub_rn(az, bz);
  return __fadd_rn(__fadd_rn(__fmul_rn(dx, dx), __fmul_rn(dy, dy)), __fmul_rn(dz, dz));
}

// merge two descending-sorted top-2 lists of packed keys -> top-2 in (a1,a2)
static __device__ __forceinline__ void merge2(u64& a1, u64& a2, u64 b1, u64 b2) {
  bool agt = a1 > b1;
  u64 m1 = agt ? a1 : b1;
  u64 lo = agt ? b1 : a1;
  u64 cs = agt ? a2 : b2;
  a1 = m1;
  a2 = lo > cs ? lo : cs;
}

static __device__ __forceinline__ u64 pack_key(float v, int i) {
  // nonneg float bits are monotone as uint; ~i gives first-index tie-break under max.
  if (v < 0.f) return 0ull;
  return ((u64)__float_as_uint(v) << 32) | (unsigned)(~i);
}

// DPP cross-lane move of a u64 (two 32-bit halves). bound_ctrl=1 -> invalid lanes read 0.
template<int CTRL>
static __device__ __forceinline__ u64 dpp_u64(u64 x) {
  unsigned lo = (unsigned)__builtin_amdgcn_update_dpp(0, (int)(unsigned)x, CTRL, 0xF, 0xF, true);
  unsigned hi = (unsigned)__builtin_amdgcn_update_dpp(0, (int)(unsigned)(x >> 32), CTRL, 0xF, 0xF, true);
  return ((u64)hi << 32) | lo;
}

template<int CTRL>
static __device__ __forceinline__ void merge_dpp(u64& a1, u64& a2) {
  u64 b1 = dpp_u64<CTRL>(a1);
  u64 b2 = dpp_u64<CTRL>(a2);
  merge2(a1, a2, b1, b2);
}

// Full-wave top-2 reduce at VALU latency; exact result lands in LANE 63.
static __device__ __forceinline__ void wave_top2_dpp(u64& a1, u64& a2) {
  merge_dpp<0xB1>(a1, a2);    // xor 1
  merge_dpp<0x4E>(a1, a2);    // xor 2
  merge_dpp<0x141>(a1, a2);   // row_half_mirror: xor 4
  merge_dpp<0x140>(a1, a2);   // row_mirror: xor 8
  merge_dpp<0x142>(a1, a2);   // row_bcast15
  merge_dpp<0x143>(a1, a2);   // row_bcast31; lane63 = full wave
}

// ---------------- FPS: 1 barrier/step, DPP top-2 argmax, top-2 speculation ----------------
// Publishes progress (rows of O written) every 32 points via agent-scope release store,
// so consumer blocks in the same launch can stream the sampled points.
template<int N, int M, int NPT, int T>
static __device__ void fps_body(const float* __restrict__ P, float* __restrict__ O,
                                char* smem, int* prog) {
  constexpr int W = T / 64;
  static_assert(N == T * NPT, "layout");
  float* xs = (float*)smem;
  float* ys = xs + N;
  float* zs = ys + N;
  uint4* slots = (uint4*)(zs + N);   // [2][W]
  const int tid = threadIdx.x;
  const int lane = tid & 63, wv = tid >> 6;

  for (int j = tid; j < N; j += T) {
    xs[j] = P[3 * j]; ys[j] = P[3 * j + 1]; zs[j] = P[3 * j + 2];
  }
  __syncthreads();

  const float c0x = xs[0], c0y = ys[0], c0z = zs[0];
  if (tid == 0) { O[0] = c0x; O[1] = c0y; O[2] = c0z; }

  float md[NPT], px[NPT], py[NPT], pz[NPT];
  float v1 = -1.f, v2 = -1.f; int i1 = 0, i2 = 0;
  #pragma unroll
  for (int k = 0; k < NPT; ++k) {
    int j = tid + k * T;  // ascending j -> '>' keeps first index on ties
    px[k] = xs[j]; py[k] = ys[j]; pz[k] = zs[j];
    float m = d2_rn(px[k], py[k], pz[k], c0x, c0y, c0z);
    md[k] = m;
    if (m > v2) { if (m > v1) { v2=v1; i2=i1; v1=m; i1=j; } else { v2=m; i2=j; } }
  }

  u64 a1 = pack_key(v1, i1), a2 = pack_key(v2, i2);
  wave_top2_dpp(a1, a2);
  if (lane == 63)
    slots[wv] = make_uint4((unsigned)a1, (unsigned)(a1 >> 32),
                           (unsigned)a2, (unsigned)(a2 >> 32));

  int t = 1, phase = 0, pub = 32;
  while (t < M) {
    __syncthreads();
    // ---- cross-wave merge: lane reads slot[lane&(W-1)]; 3 DPP levels -> global top-2
    uint4 s = slots[phase * W + (lane & (W - 1))];
    a1 = ((u64)s.y << 32) | s.x;
    a2 = ((u64)s.w << 32) | s.z;
    merge_dpp<0xB1>(a1, a2);   // xor 1
    merge_dpp<0x4E>(a1, a2);   // xor 2
    merge_dpp<0x141>(a1, a2);  // xor 4 (8 slots fully merged, uniform everywhere)

    const int j1 = (int)(~(unsigned)a1);
    const float c1x = xs[j1], c1y = ys[j1], c1z = zs[j1];
    const float v2f = __uint_as_float((unsigned)(a2 >> 32));

    bool hit = false;
    float c2x = 0.f, c2y = 0.f, c2z = 0.f;
    if (t + 1 < M && v2f > 0.f) {
      int j2 = (int)(~(unsigned)a2);
      c2x = xs[j2]; c2y = ys[j2]; c2z = zs[j2];
      float dd = d2_rn(c2x, c2y, c2z, c1x, c1y, c1z);
      hit = (dd >= v2f);   // then md'[j2]=v2 stays the exact (val,first-idx) max
    }

    if (tid == 0) {
      O[3 * t] = c1x; O[3 * t + 1] = c1y; O[3 * t + 2] = c1z;
      if (hit) { O[3 * t + 3] = c2x; O[3 * t + 4] = c2y; O[3 * t + 5] = c2z; }
    }

    v1 = -1.f; v2 = -1.f; i1 = 0; i2 = 0;
    if (hit) {
      #pragma unroll
      for (int k = 0; k < NPT; ++k) {
        float m = md[k];
        m = fminf(m, d2_rn(px[k], py[k], pz[k], c1x, c1y, c1z));
        m = fminf(m, d2_rn(px[k], py[k], pz[k], c2x, c2y, c2z));
        md[k] = m;
        int j = tid + k * T;
        if (m > v2) { if (m > v1) { v2=v1; i2=i1; v1=m; i1=j; } else { v2=m; i2=j; } }
      }
    } else {
      #pragma unroll
      for (int k = 0; k < NPT; ++k) {
        float m = fminf(md[k], d2_rn(px[k], py[k], pz[k], c1x, c1y, c1z));
        md[k] = m;
        int j = tid + k * T;
        if (m > v2) { if (m > v1) { v2=v1; i2=i1; v1=m; i1=j; } else { v2=m; i2=j; } }
      }
    }

    a1 = pack_key(v1, i1); a2 = pack_key(v2, i2);
    wave_top2_dpp(a1, a2);
    if (lane == 63)
      slots[(phase ^ 1) * W + wv] = make_uint4((unsigned)a1, (unsigned)(a1 >> 32),
                                               (unsigned)a2, (unsigned)(a2 >> 32));
    phase ^= 1;
    t += hit ? 2 : 1;
    if (tid == 0 && t >= pub) {   // amortized publish (release drains tid0's O stores)
      __hip_atomic_store(prog, t, __ATOMIC_RELEASE, __HIP_MEMORY_SCOPE_AGENT);
      pub = t + 32;
    }
  }
  if (tid == 0)
    __hip_atomic_store(prog, M, __ATOMIC_RELEASE, __HIP_MEMORY_SCOPE_AGENT);
}

// ------------- per-source g[j] = x_j @ W1x + pos_j @ W1p  (tiny GEMM) -------------
template<int C, int H>
__global__ void g_kernel(const float* __restrict__ x, const float* __restrict__ pos,
                         const float* __restrict__ W, float* __restrict__ g, int rows) {
  int idx = blockIdx.x * 256 + threadIdx.x;
  if (idx >= rows * H) return;
  int row = idx / H, h = idx - row * H;
  const float* xr = x + (size_t)row * C;
  const float* pr = pos + (size_t)row * 3;
  float acc = 0.f;
  for (int c = 0; c < C; ++c) acc = fmaf(xr[c], W[c * H + h], acc);
  #pragma unroll
  for (int c = 0; c < 3; ++c) acc = fmaf(pr[c], W[(C + c) * H + h], acc);
  g[idx] = acc;
}

// ---------------- SA layer body (templated on thread count T) ----------------
template<int N, int H, int C, int T>
constexpr int sa_smem_bytes() {
  constexpr int TPS = C / 2, SG = T / TPS, JT = SG * 4, STRIDE = JT + 4;
  constexpr int SCR = (SG * C > 512) ? SG * C : 512;
  return H * C * 2 + N * 4 + H * 4 + STRIDE * H * 4 + SCR * 4 + 64 * 4 + 8 * 4 + 8 * 4;
}

template<int N, int H, int C, int QB, int T>
static __device__ void sa_body(const float* __restrict__ srcb,  // [N,3]
                               const float* __restrict__ gb,    // [N,H]
                               const float* __restrict__ qposb, // [M,3] (may be streaming)
                               const float* __restrict__ W2, const float* __restrict__ b1v,
                               const float* __restrict__ W1p, const float* __restrict__ b2v,
                               float r2, int M, float* __restrict__ outb, int qtile,
                               char* smem, const int* prog) {
  constexpr int TPS = C / 2;
  constexpr int SG  = T / TPS;
  constexpr int JT  = SG * 4;
  constexpr int STRIDE = JT + 4;
  constexpr int SCR = (SG * C > 512) ? SG * C : 512;
  const int tid = threadIdx.x;
  const int sgi = tid / TPS;
  const int c2 = 2 * (tid - sgi * TPS);

  __hip_bfloat16* sW2h = (__hip_bfloat16*)smem;          // H*C*2
  float* sD2  = (float*)(smem + H * C * 2);              // N
  float* sT   = sD2 + N;                                 // H
  float* sHj  = sT + H;                                  // STRIDE*H (16B aligned)
  float* sScr = sHj + STRIDE * H;                        // SCR
  int*   sNbr = (int*)(sScr + SCR);                      // 64
  int*   sWS  = sNbr + 64;                               // 8
  int*   sIv  = sWS + 8;   // [0]=Cnt [1]=Nn [2]=Nc [3]=Bin [4]=Before [5]=TauI
  float* sFv  = (float*)(sIv + 6);  // [0]=TauV

  int*   sHist  = (int*)sScr;
  float* sCand  = sScr + 256;
  int*   sCandI = (int*)(sScr + 320);
  float* sRed   = sScr;

  for (int e = tid; e < H * C; e += T) sW2h[e] = __float2bfloat16(W2[e]);

  for (int qi = 0; qi < QB; ++qi) {
    const int i = qtile * QB + qi;
    // ---- streaming gate: wait until producer has written row i ----
    if (prog) {
      const int need = i + 1;
      const int lane = tid & 63;
      int pv;
      do {
        int v = 0;
        if (lane == 0)
          v = __hip_atomic_load(prog, __ATOMIC_ACQUIRE, __HIP_MEMORY_SCOPE_AGENT);
        pv = __builtin_amdgcn_readfirstlane(v);
        if (pv < need) __builtin_amdgcn_s_sleep(16);
      } while (pv < need);
    }
    const float* qp = qposb + (size_t)i * 3;
    float qx, qy, qz;
    if (prog) {   // coherent reads (bypass possibly-stale caches; producer released)
      qx = __hip_atomic_load(qp + 0, __ATOMIC_RELAXED, __HIP_MEMORY_SCOPE_AGENT);
      qy = __hip_atomic_load(qp + 1, __ATOMIC_RELAXED, __HIP_MEMORY_SCOPE_AGENT);
      qz = __hip_atomic_load(qp + 2, __ATOMIC_RELAXED, __HIP_MEMORY_SCOPE_AGENT);
    } else {
      qx = qp[0]; qy = qp[1]; qz = qp[2];
    }
    const float qq = __fadd_rn(__fadd_rn(__fmul_rn(qx, qx), __fmul_rn(qy, qy)),
                               __fmul_rn(qz, qz));
    if (tid < H)
      sT[tid] = fmaf(qx, W1p[tid], fmaf(qy, W1p[H + tid], fmaf(qz, W1p[2 * H + tid], -b1v[tid])));
    if (tid == 0) { sIv[0] = 0; sIv[1] = 0; sIv[2] = 0; }
    if (tid < 256) sHist[tid] = 0;
    __syncthreads();

    // ---- pass 1: d2 (reference formula, exact rounding) + in-radius count ----
    int lc = 0;
    for (int j = tid; j < N; j += T) {
      float sx = srcb[3 * j], sy = srcb[3 * j + 1], sz = srcb[3 * j + 2];
      float ss  = __fadd_rn(__fadd_rn(__fmul_rn(sx, sx), __fmul_rn(sy, sy)), __fmul_rn(sz, sz));
      float dot = __fadd_rn(__fadd_rn(__fmul_rn(qx, sx), __fmul_rn(qy, sy)), __fmul_rn(qz, sz));
      float d2  = __fsub_rn(__fadd_rn(qq, ss), __fmul_rn(2.0f, dot));
      sD2[j] = d2;
      lc += (d2 <= r2) ? 1 : 0;
    }
    #pragma unroll
    for (int off = 32; off > 0; off >>= 1) lc += __shfl_xor(lc, off, 64);
    if ((tid & 63) == 0) atomicAdd(&sIv[0], lc);
    __syncthreads();
    const int cnt = sIv[0];

    // ---- exact rank-64 threshold (lexicographic (d2, idx), matches lax.top_k) ----
    float tauv; int taui;
    if (cnt <= 64) {
      tauv = r2; taui = 0x7fffffff;
    } else {
      const float scale = 256.0f / r2;
      for (int j = tid; j < N; j += T) {
        float d2 = sD2[j];
        if (d2 <= r2) {
          int bin = (int)(d2 * scale);
          bin = bin < 0 ? 0 : (bin > 255 ? 255 : bin);
          atomicAdd(&sHist[bin], 1);
        }
      }
      __syncthreads();
      int cbin = (tid < 256) ? sHist[tid] : 0;
      int lane = tid & 63, wvi = tid >> 6;
      int v = cbin;
      #pragma unroll
      for (int off = 1; off < 64; off <<= 1) {
        int o = __shfl_up(v, off, 64);
        if (lane >= off) v += o;
      }
      if (lane == 63) sWS[wvi] = v;
      __syncthreads();
      int wadd = 0;
      for (int w = 0; w < wvi; ++w) wadd += sWS[w];
      int incl = v + wadd, excl = incl - cbin;
      if (tid < 256 && excl < 64 && incl >= 64) { sIv[3] = tid; sIv[4] = excl; }
      __syncthreads();
      const int bstar = sIv[3];
      const int kneed = 64 - sIv[4];
      for (int j = tid; j < N; j += T) {
        float d2 = sD2[j];
        if (d2 <= r2) {
          int bin = (int)(d2 * scale);
          bin = bin < 0 ? 0 : (bin > 255 ? 255 : bin);
          if (bin == bstar) {
            int p = atomicAdd(&sIv[2], 1);
            if (p < 64) { sCand[p] = d2; sCandI[p] = j; }
          }
        }
      }
      __syncthreads();
      if (tid == 0) {
        int nc = sIv[2] < 64 ? sIv[2] : 64;
        for (int a = 1; a < nc; ++a) {
          float dv = sCand[a]; int di = sCandI[a];
          int p = a - 1;
          while (p >= 0 && (sCand[p] > dv || (sCand[p] == dv && sCandI[p] > di))) {
            sCand[p + 1] = sCand[p]; sCandI[p + 1] = sCandI[p]; --p;
          }
          sCand[p + 1] = dv; sCandI[p + 1] = di;
        }
        int kk = (kneed < nc ? kneed : nc) - 1; if (kk < 0) kk = 0;
        sFv[0] = sCand[kk]; sIv[5] = sCandI[kk];
      }
      __syncthreads();
      tauv = sFv[0]; taui = sIv[5];
    }

    // ---- compact neighbor list (set membership only; order irrelevant for max) ----
    for (int j = tid; j < N; j += T) {
      float d2 = sD2[j];
      if (d2 < tauv || (d2 == tauv && j <= taui)) {
        int p = atomicAdd(&sIv[1], 1);
        if (p < 64) sNbr[p] = j;
      }
    }
    __syncthreads();
    const int nn = sIv[1] < 64 ? sIv[1] : 64;

    // ---- MLP: h = ReLU(g[j]-t[i]);  out_c = max_j (h @ W2)_c + b2_c ----
    float m0 = -FLT_MAX, m1 = -FLT_MAX;
    for (int t0 = 0; t0 < nn; t0 += JT) {
      int jt = nn - t0; if (jt > JT) jt = JT;
      __syncthreads();
      for (int e = tid; e < JT * H; e += T) {
        int jj = e / H, h = e - jj * H;
        float hv = 0.f;
        if (jj < jt) {
          int j = sNbr[t0 + jj];
          hv = gb[(size_t)j * H + h] - sT[h];
          hv = hv > 0.f ? hv : 0.f;
        }
        sHj[h * STRIDE + jj] = hv;
      }
      __syncthreads();
      float a0 = 0, a1 = 0, a2 = 0, a3 = 0, c0 = 0, c1 = 0, c2a = 0, c3 = 0;
      const int jbase = sgi * 4;
      for (int h = 0; h < H; ++h) {
        float4 hv = *reinterpret_cast<const float4*>(&sHj[h * STRIDE + jbase]);
        __hip_bfloat162 wp = *reinterpret_cast<const __hip_bfloat162*>(&sW2h[h * C + c2]);
        float wx = __bfloat162float(wp.x), wy = __bfloat162float(wp.y);
        a0 = fmaf(hv.x, wx, a0); a1 = fmaf(hv.y, wx, a1);
        a2 = fmaf(hv.z, wx, a2); a3 = fmaf(hv.w, wx, a3);
        c0 = fmaf(hv.x, wy, c0); c1 = fmaf(hv.y, wy, c1);
        c2a = fmaf(hv.z, wy, c2a); c3 = fmaf(hv.w, wy, c3);
      }
      if (jbase + 0 < jt) { m0 = fmaxf(m0, a0); m1 = fmaxf(m1, c0); }
      if (jbase + 1 < jt) { m0 = fmaxf(m0, a1); m1 = fmaxf(m1, c1); }
      if (jbase + 2 < jt) { m0 = fmaxf(m0, a2); m1 = fmaxf(m1, c2a); }
      if (jbase + 3 < jt) { m0 = fmaxf(m0, a3); m1 = fmaxf(m1, c3); }
    }
    __syncthreads();
    sRed[sgi * C + c2]     = m0;
    sRed[sgi * C + c2 + 1] = m1;
    __syncthreads();
    if (tid < TPS) {
      int c = 2 * tid;
      float M0 = sRed[c], M1 = sRed[c + 1];
      #pragma unroll
      for (int s2 = 1; s2 < SG; ++s2) {
        M0 = fmaxf(M0, sRed[s2 * C + c]);
        M1 = fmaxf(M1, sRed[s2 * C + c + 1]);
      }
      float o0 = nn > 0 ? M0 + b2v[c]     : 0.f;
      float o1 = nn > 0 ? M1 + b2v[c + 1] : 0.f;
      float* orow = outb + (size_t)i * C;
      orow[c] = o0; orow[c + 1] = o1;
    }
    __syncthreads();
  }
}

// ------- mega: blocks 0-7 = FPS producer (prio 3); rest = persistent SA consumers -------
// SA consumes THIS fps's output as its query set (M = MF), streaming via prog[b].
template<int NF, int MF, int NPTF, int NS, int HS, int CS, int QB, int NC>
__global__ __launch_bounds__(512, 2) void mega_kernel(
    const float* __restrict__ fsrc, float* __restrict__ fdst, int* __restrict__ prog,
    const float* __restrict__ src, const float* __restrict__ g,
    const float* __restrict__ W2, const float* __restrict__ b1v,
    const float* __restrict__ W1p, const float* __restrict__ b2v,
    float r2, float* __restrict__ out) {
  constexpr int FPS_BYTES = 12 * NF + 256;
  constexpr int SA_BYTES  = sa_smem_bytes<NS, HS, CS, 512>();
  constexpr int SMEM = FPS_BYTES > SA_BYTES ? FPS_BYTES : SA_BYTES;
  constexpr int TT = 8 * (MF / QB);   // total sa tiles
  __shared__ __align__(16) char smem[SMEM];
  if (blockIdx.x < 8) {
    __builtin_amdgcn_s_setprio(3);  // FPS is the latency-critical serial chain
    fps_body<NF, MF, NPTF, 512>(fsrc + (size_t)blockIdx.x * NF * 3,
                                fdst + (size_t)blockIdx.x * MF * 3, smem,
                                prog + blockIdx.x);
    return;
  }
  const int cons = blockIdx.x - 8;
  for (int tt = cons; tt < TT; tt += NC) {   // ascending qt -> streams with producer
    const int qt = tt >> 3, b = tt & 7;
    sa_body<NS, HS, CS, QB, 512>(src + (size_t)b * NS * 3, g + (size_t)b * NS * HS,
                                 fdst + (size_t)b * MF * 3, W2, b1v, W1p, b2v, r2, MF,
                                 out + (size_t)b * MF * CS, qt, smem, prog + b);
  }
}

// ---------------- tail: copy p3 and synthesize batch ids into d_out ----------------
__global__ void tail_kernel(const float* __restrict__ p3, float* __restrict__ d_out) {
  int i = blockIdx.x * 256 + threadIdx.x;
  if (i < 8 * 512 * 3) d_out[524288 + i] = p3[i];
  if (i < 8 * 512)     d_out[536576 + i] = (float)(i >> 9);
}

extern "C" void kernel_launch(void* const* d_in, const int* in_sizes, int n_in,
                              void* d_out, int out_size, void* d_ws, size_t ws_size,
                              hipStream_t stream) {
  (void)in_sizes; (void)n_in; (void)out_size; (void)ws_size;
  const float* pos = (const float*)d_in[0];
  const float* w11 = (const float*)d_in[2];
  const float* b11 = (const float*)d_in[3];
  const float* w12 = (const float*)d_in[4];
  const float* b12 = (const float*)d_in[5];
  const float* w21 = (const float*)d_in[6];
  const float* b21 = (const float*)d_in[7];
  const float* w22 = (const float*)d_in[8];
  const float* b22 = (const float*)d_in[9];
  const float* w31 = (const float*)d_in[10];
  const float* b31 = (const float*)d_in[11];
  const float* w32 = (const float*)d_in[12];
  const float* b32 = (const float*)d_in[13];

  float* ws = (float*)d_ws;
  float* p1 = ws; ws += 8 * 2048 * 3;
  float* p2 = ws; ws += 8 * 512 * 3;
  float* p3 = ws; ws += 8 * 512 * 3;
  float* g1 = ws; ws += 8 * 4096 * 32;
  float* x1 = ws; ws += 8 * 2048 * 32;
  float* g2 = ws; ws += 8 * 2048 * 64;
  float* x2 = ws; ws += 8 * 512 * 64;
  float* g3 = ws; ws += 8 * 512 * 128;
  int* prog1 = (int*)ws; ws += 8;   // poison 0xAA.. is negative -> consumers spin
  int* prog2 = (int*)ws; ws += 8;
  int* prog3 = (int*)ws; ws += 8;
  float* x3 = (float*)d_out;

  // g1 first (independent of fps1)
  g_kernel<3, 32><<<dim3(8 * 4096 * 32 / 256), dim3(256), 0, stream>>>(pos, pos, w11, g1, 8 * 4096);

  // mega1: fps1 (pos -> p1) with sa1 streaming p1 rows (pos,g1,p1 -> x1)
  mega_kernel<4096, 2048, 8, 4096, 32, 32, 8, 760><<<dim3(768), dim3(512), 0, stream>>>(
      pos, p1, prog1, pos, g1, w12, b11, w11 + 3 * 32, b12, 0.04f, x1);

  g_kernel<32, 64><<<dim3(8 * 2048 * 64 / 256), dim3(256), 0, stream>>>(x1, p1, w21, g2, 8 * 2048);

  // mega2: fps2 (p1 -> p2) with sa2 streaming p2 rows (p1,g2,p2 -> x2)
  mega_kernel<2048, 512, 4, 2048, 64, 64, 8, 512><<<dim3(520), dim3(512), 0, stream>>>(
      p1, p2, prog2, p1, g2, w22, b21, w21 + 32 * 64, b22, 0.16f, x2);

  g_kernel<64, 128><<<dim3(8 * 512 * 128 / 256), dim3(256), 0, stream>>>(x2, p2, w31, g3, 8 * 512);

  // mega3: fps3 (p2 -> p3) with sa3 streaming p3 rows (p2,g3,p3 -> x3)
  mega_kernel<512, 512, 1, 512, 128, 128, 8, 504><<<dim3(512), dim3(512), 0, stream>>>(
      p2, p3, prog3, p2, g3, w32, b31, w31 + 64 * 128, b32, 1.0f, x3);

  tail_kernel<<<dim3(48), dim3(256), 0, stream>>>(p3, (float*)d_out);
}

// Round 9
// 2597.456 us; speedup vs baseline: 1.3613x; 1.3613x over previous
//
#include <hip/hip_runtime.h>
#include <hip/hip_bf16.h>
#include <float.h>

typedef unsigned long long u64;

// ---------- exact-rounding helpers (match numpy fp32, no FMA contraction) ----------
static __device__ __forceinline__ float d2_rn(float ax, float ay, float az,
                                              float bx, float by, float bz) {
  float dx = __fsub_rn(ax, bx), dy = __fsub_rn(ay, by), dz = __fsub_rn(az, bz);
  return __fadd_rn(__fadd_rn(__fmul_rn(dx, dx), __fmul_rn(dy, dy)), __fmul_rn(dz, dz));
}

// merge two descending-sorted top-2 lists of packed keys -> top-2 in (a1,a2)
static __device__ __forceinline__ void merge2(u64& a1, u64& a2, u64 b1, u64 b2) {
  bool agt = a1 > b1;
  u64 m1 = agt ? a1 : b1;
  u64 lo = agt ? b1 : a1;
  u64 cs = agt ? a2 : b2;
  a1 = m1;
  a2 = lo > cs ? lo : cs;
}

static __device__ __forceinline__ u64 pack_key(float v, int i) {
  // nonneg float bits are monotone as uint; ~i gives first-index tie-break under max.
  if (v < 0.f) return 0ull;
  return ((u64)__float_as_uint(v) << 32) | (unsigned)(~i);
}

// DPP cross-lane move of a u64 (two 32-bit halves). bound_ctrl=1 -> invalid lanes read 0.
template<int CTRL>
static __device__ __forceinline__ u64 dpp_u64(u64 x) {
  unsigned lo = (unsigned)__builtin_amdgcn_update_dpp(0, (int)(unsigned)x, CTRL, 0xF, 0xF, true);
  unsigned hi = (unsigned)__builtin_amdgcn_update_dpp(0, (int)(unsigned)(x >> 32), CTRL, 0xF, 0xF, true);
  return ((u64)hi << 32) | lo;
}

template<int CTRL>
static __device__ __forceinline__ void merge_dpp(u64& a1, u64& a2) {
  u64 b1 = dpp_u64<CTRL>(a1);
  u64 b2 = dpp_u64<CTRL>(a2);
  merge2(a1, a2, b1, b2);
}

// Full-wave top-2 reduce at VALU latency; exact result lands in LANE 63.
static __device__ __forceinline__ void wave_top2_dpp(u64& a1, u64& a2) {
  merge_dpp<0xB1>(a1, a2);    // xor 1
  merge_dpp<0x4E>(a1, a2);    // xor 2
  merge_dpp<0x141>(a1, a2);   // row_half_mirror: xor 4
  merge_dpp<0x140>(a1, a2);   // row_mirror: xor 8
  merge_dpp<0x142>(a1, a2);   // row_bcast15
  merge_dpp<0x143>(a1, a2);   // row_bcast31; lane63 = full wave
}

// ---------------- FPS: 1 barrier/step, DPP top-2 argmax, top-2 speculation ----------------
// Publishes progress (rows of O written) every 32 points via agent-scope release store,
// so consumer blocks in the same launch can stream the sampled points.
template<int N, int M, int NPT, int T>
static __device__ void fps_body(const float* __restrict__ P, float* __restrict__ O,
                                char* smem, int* prog) {
  constexpr int W = T / 64;
  static_assert(N == T * NPT, "layout");
  float* xs = (float*)smem;
  float* ys = xs + N;
  float* zs = ys + N;
  uint4* slots = (uint4*)(zs + N);   // [2][W]
  const int tid = threadIdx.x;
  const int lane = tid & 63, wv = tid >> 6;

  for (int j = tid; j < N; j += T) {
    xs[j] = P[3 * j]; ys[j] = P[3 * j + 1]; zs[j] = P[3 * j + 2];
  }
  __syncthreads();

  const float c0x = xs[0], c0y = ys[0], c0z = zs[0];
  if (tid == 0) { O[0] = c0x; O[1] = c0y; O[2] = c0z; }

  float md[NPT], px[NPT], py[NPT], pz[NPT];
  float v1 = -1.f, v2 = -1.f; int i1 = 0, i2 = 0;
  #pragma unroll
  for (int k = 0; k < NPT; ++k) {
    int j = tid + k * T;  // ascending j -> '>' keeps first index on ties
    px[k] = xs[j]; py[k] = ys[j]; pz[k] = zs[j];
    float m = d2_rn(px[k], py[k], pz[k], c0x, c0y, c0z);
    md[k] = m;
    if (m > v2) { if (m > v1) { v2=v1; i2=i1; v1=m; i1=j; } else { v2=m; i2=j; } }
  }

  u64 a1 = pack_key(v1, i1), a2 = pack_key(v2, i2);
  wave_top2_dpp(a1, a2);
  if (lane == 63)
    slots[wv] = make_uint4((unsigned)a1, (unsigned)(a1 >> 32),
                           (unsigned)a2, (unsigned)(a2 >> 32));

  int t = 1, phase = 0, pub = 32;
  while (t < M) {
    __syncthreads();
    // ---- cross-wave merge: lane reads slot[lane&(W-1)]; 3 DPP levels -> global top-2
    uint4 s = slots[phase * W + (lane & (W - 1))];
    a1 = ((u64)s.y << 32) | s.x;
    a2 = ((u64)s.w << 32) | s.z;
    merge_dpp<0xB1>(a1, a2);   // xor 1
    merge_dpp<0x4E>(a1, a2);   // xor 2
    merge_dpp<0x141>(a1, a2);  // xor 4 (8 slots fully merged, uniform everywhere)

    const int j1 = (int)(~(unsigned)a1);
    const float c1x = xs[j1], c1y = ys[j1], c1z = zs[j1];
    const float v2f = __uint_as_float((unsigned)(a2 >> 32));

    bool hit = false;
    float c2x = 0.f, c2y = 0.f, c2z = 0.f;
    if (t + 1 < M && v2f > 0.f) {
      int j2 = (int)(~(unsigned)a2);
      c2x = xs[j2]; c2y = ys[j2]; c2z = zs[j2];
      float dd = d2_rn(c2x, c2y, c2z, c1x, c1y, c1z);
      hit = (dd >= v2f);   // then md'[j2]=v2 stays the exact (val,first-idx) max
    }

    if (tid == 0) {
      O[3 * t] = c1x; O[3 * t + 1] = c1y; O[3 * t + 2] = c1z;
      if (hit) { O[3 * t + 3] = c2x; O[3 * t + 4] = c2y; O[3 * t + 5] = c2z; }
    }

    v1 = -1.f; v2 = -1.f; i1 = 0; i2 = 0;
    if (hit) {
      #pragma unroll
      for (int k = 0; k < NPT; ++k) {
        float m = md[k];
        m = fminf(m, d2_rn(px[k], py[k], pz[k], c1x, c1y, c1z));
        m = fminf(m, d2_rn(px[k], py[k], pz[k], c2x, c2y, c2z));
        md[k] = m;
        int j = tid + k * T;
        if (m > v2) { if (m > v1) { v2=v1; i2=i1; v1=m; i1=j; } else { v2=m; i2=j; } }
      }
    } else {
      #pragma unroll
      for (int k = 0; k < NPT; ++k) {
        float m = fminf(md[k], d2_rn(px[k], py[k], pz[k], c1x, c1y, c1z));
        md[k] = m;
        int j = tid + k * T;
        if (m > v2) { if (m > v1) { v2=v1; i2=i1; v1=m; i1=j; } else { v2=m; i2=j; } }
      }
    }

    a1 = pack_key(v1, i1); a2 = pack_key(v2, i2);
    wave_top2_dpp(a1, a2);
    if (lane == 63)
      slots[(phase ^ 1) * W + wv] = make_uint4((unsigned)a1, (unsigned)(a1 >> 32),
                                               (unsigned)a2, (unsigned)(a2 >> 32));
    phase ^= 1;
    t += hit ? 2 : 1;
    if (tid == 0 && t >= pub) {   // amortized publish (release drains tid0's O stores)
      __hip_atomic_store(prog, t, __ATOMIC_RELEASE, __HIP_MEMORY_SCOPE_AGENT);
      pub = t + 32;
    }
  }
  if (tid == 0)
    __hip_atomic_store(prog, M, __ATOMIC_RELEASE, __HIP_MEMORY_SCOPE_AGENT);
}

// ------------- per-source g[j] = x_j @ W1x + pos_j @ W1p  (tiny GEMM) -------------
template<int C, int H>
__global__ void g_kernel(const float* __restrict__ x, const float* __restrict__ pos,
                         const float* __restrict__ W, float* __restrict__ g, int rows) {
  int idx = blockIdx.x * 256 + threadIdx.x;
  if (idx >= rows * H) return;
  int row = idx / H, h = idx - row * H;
  const float* xr = x + (size_t)row * C;
  const float* pr = pos + (size_t)row * 3;
  float acc = 0.f;
  for (int c = 0; c < C; ++c) acc = fmaf(xr[c], W[c * H + h], acc);
  #pragma unroll
  for (int c = 0; c < 3; ++c) acc = fmaf(pr[c], W[(C + c) * H + h], acc);
  g[idx] = acc;
}

// ---------------- SA layer body (templated on thread count T) ----------------
template<int N, int H, int C, int T>
constexpr int sa_smem_bytes() {
  constexpr int TPS = C / 2, SG = T / TPS, JT = SG * 4, STRIDE = JT + 4;
  constexpr int SCR = (SG * C > 512) ? SG * C : 512;
  return H * C * 2 + N * 4 + H * 4 + STRIDE * H * 4 + SCR * 4 + 64 * 4 + 8 * 4 + 8 * 4;
}

template<int N, int H, int C, int QB, int T>
static __device__ void sa_body(const float* __restrict__ srcb,  // [N,3]
                               const float* __restrict__ gb,    // [N,H]
                               const float* __restrict__ qposb, // [M,3] (may be streaming)
                               const float* __restrict__ W2, const float* __restrict__ b1v,
                               const float* __restrict__ W1p, const float* __restrict__ b2v,
                               float r2, int M, float* __restrict__ outb, int qtile,
                               char* smem, const int* prog) {
  constexpr int TPS = C / 2;
  constexpr int SG  = T / TPS;
  constexpr int JT  = SG * 4;
  constexpr int STRIDE = JT + 4;
  constexpr int SCR = (SG * C > 512) ? SG * C : 512;
  const int tid = threadIdx.x;
  const int sgi = tid / TPS;
  const int c2 = 2 * (tid - sgi * TPS);

  __hip_bfloat16* sW2h = (__hip_bfloat16*)smem;          // H*C*2
  float* sD2  = (float*)(smem + H * C * 2);              // N
  float* sT   = sD2 + N;                                 // H
  float* sHj  = sT + H;                                  // STRIDE*H (16B aligned)
  float* sScr = sHj + STRIDE * H;                        // SCR
  int*   sNbr = (int*)(sScr + SCR);                      // 64
  int*   sWS  = sNbr + 64;                               // 8
  int*   sIv  = sWS + 8;   // [0]=Cnt [1]=Nn [2]=Nc [3]=Bin [4]=Before [5]=TauI
  float* sFv  = (float*)(sIv + 6);  // [0]=TauV

  int*   sHist  = (int*)sScr;
  float* sCand  = sScr + 256;
  int*   sCandI = (int*)(sScr + 320);
  float* sRed   = sScr;

  for (int e = tid; e < H * C; e += T) sW2h[e] = __float2bfloat16(W2[e]);

  for (int qi = 0; qi < QB; ++qi) {
    const int i = qtile * QB + qi;
    // ---- streaming gate: wait until producer has written row i ----
    if (prog) {
      const int need = i + 1;
      const int lane = tid & 63;
      int pv;
      do {
        int v = 0;
        if (lane == 0)
          v = __hip_atomic_load(prog, __ATOMIC_ACQUIRE, __HIP_MEMORY_SCOPE_AGENT);
        pv = __builtin_amdgcn_readfirstlane(v);
        if (pv < need) __builtin_amdgcn_s_sleep(16);
      } while (pv < need);
    }
    const float* qp = qposb + (size_t)i * 3;
    float qx, qy, qz;
    if (prog) {   // coherent reads (bypass possibly-stale caches; producer released)
      qx = __hip_atomic_load(qp + 0, __ATOMIC_RELAXED, __HIP_MEMORY_SCOPE_AGENT);
      qy = __hip_atomic_load(qp + 1, __ATOMIC_RELAXED, __HIP_MEMORY_SCOPE_AGENT);
      qz = __hip_atomic_load(qp + 2, __ATOMIC_RELAXED, __HIP_MEMORY_SCOPE_AGENT);
    } else {
      qx = qp[0]; qy = qp[1]; qz = qp[2];
    }
    const float qq = __fadd_rn(__fadd_rn(__fmul_rn(qx, qx), __fmul_rn(qy, qy)),
                               __fmul_rn(qz, qz));
    if (tid < H)
      sT[tid] = fmaf(qx, W1p[tid], fmaf(qy, W1p[H + tid], fmaf(qz, W1p[2 * H + tid], -b1v[tid])));
    if (tid == 0) { sIv[0] = 0; sIv[1] = 0; sIv[2] = 0; }
    if (tid < 256) sHist[tid] = 0;
    __syncthreads();

    // ---- pass 1: d2 (reference formula, exact rounding) + in-radius count ----
    int lc = 0;
    for (int j = tid; j < N; j += T) {
      float sx = srcb[3 * j], sy = srcb[3 * j + 1], sz = srcb[3 * j + 2];
      float ss  = __fadd_rn(__fadd_rn(__fmul_rn(sx, sx), __fmul_rn(sy, sy)), __fmul_rn(sz, sz));
      float dot = __fadd_rn(__fadd_rn(__fmul_rn(qx, sx), __fmul_rn(qy, sy)), __fmul_rn(qz, sz));
      float d2  = __fsub_rn(__fadd_rn(qq, ss), __fmul_rn(2.0f, dot));
      sD2[j] = d2;
      lc += (d2 <= r2) ? 1 : 0;
    }
    #pragma unroll
    for (int off = 32; off > 0; off >>= 1) lc += __shfl_xor(lc, off, 64);
    if ((tid & 63) == 0) atomicAdd(&sIv[0], lc);
    __syncthreads();
    const int cnt = sIv[0];

    // ---- exact rank-64 threshold (lexicographic (d2, idx), matches lax.top_k) ----
    float tauv; int taui;
    if (cnt <= 64) {
      tauv = r2; taui = 0x7fffffff;
    } else {
      const float scale = 256.0f / r2;
      for (int j = tid; j < N; j += T) {
        float d2 = sD2[j];
        if (d2 <= r2) {
          int bin = (int)(d2 * scale);
          bin = bin < 0 ? 0 : (bin > 255 ? 255 : bin);
          atomicAdd(&sHist[bin], 1);
        }
      }
      __syncthreads();
      int cbin = (tid < 256) ? sHist[tid] : 0;
      int lane = tid & 63, wvi = tid >> 6;
      int v = cbin;
      #pragma unroll
      for (int off = 1; off < 64; off <<= 1) {
        int o = __shfl_up(v, off, 64);
        if (lane >= off) v += o;
      }
      if (lane == 63) sWS[wvi] = v;
      __syncthreads();
      int wadd = 0;
      for (int w = 0; w < wvi; ++w) wadd += sWS[w];
      int incl = v + wadd, excl = incl - cbin;
      if (tid < 256 && excl < 64 && incl >= 64) { sIv[3] = tid; sIv[4] = excl; }
      __syncthreads();
      const int bstar = sIv[3];
      const int kneed = 64 - sIv[4];
      for (int j = tid; j < N; j += T) {
        float d2 = sD2[j];
        if (d2 <= r2) {
          int bin = (int)(d2 * scale);
          bin = bin < 0 ? 0 : (bin > 255 ? 255 : bin);
          if (bin == bstar) {
            int p = atomicAdd(&sIv[2], 1);
            if (p < 64) { sCand[p] = d2; sCandI[p] = j; }
          }
        }
      }
      __syncthreads();
      if (tid == 0) {
        int nc = sIv[2] < 64 ? sIv[2] : 64;
        for (int a = 1; a < nc; ++a) {
          float dv = sCand[a]; int di = sCandI[a];
          int p = a - 1;
          while (p >= 0 && (sCand[p] > dv || (sCand[p] == dv && sCandI[p] > di))) {
            sCand[p + 1] = sCand[p]; sCandI[p + 1] = sCandI[p]; --p;
          }
          sCand[p + 1] = dv; sCandI[p + 1] = di;
        }
        int kk = (kneed < nc ? kneed : nc) - 1; if (kk < 0) kk = 0;
        sFv[0] = sCand[kk]; sIv[5] = sCandI[kk];
      }
      __syncthreads();
      tauv = sFv[0]; taui = sIv[5];
    }

    // ---- compact neighbor list (set membership only; order irrelevant for max) ----
    for (int j = tid; j < N; j += T) {
      float d2 = sD2[j];
      if (d2 < tauv || (d2 == tauv && j <= taui)) {
        int p = atomicAdd(&sIv[1], 1);
        if (p < 64) sNbr[p] = j;
      }
    }
    __syncthreads();
    const int nn = sIv[1] < 64 ? sIv[1] : 64;

    // ---- MLP: h = ReLU(g[j]-t[i]);  out_c = max_j (h @ W2)_c + b2_c ----
    float m0 = -FLT_MAX, m1 = -FLT_MAX;
    for (int t0 = 0; t0 < nn; t0 += JT) {
      int jt = nn - t0; if (jt > JT) jt = JT;
      __syncthreads();
      for (int e = tid; e < JT * H; e += T) {
        int jj = e / H, h = e - jj * H;
        float hv = 0.f;
        if (jj < jt) {
          int j = sNbr[t0 + jj];
          hv = gb[(size_t)j * H + h] - sT[h];
          hv = hv > 0.f ? hv : 0.f;
        }
        sHj[h * STRIDE + jj] = hv;
      }
      __syncthreads();
      float a0 = 0, a1 = 0, a2 = 0, a3 = 0, c0 = 0, c1 = 0, c2a = 0, c3 = 0;
      const int jbase = sgi * 4;
      for (int h = 0; h < H; ++h) {
        float4 hv = *reinterpret_cast<const float4*>(&sHj[h * STRIDE + jbase]);
        __hip_bfloat162 wp = *reinterpret_cast<const __hip_bfloat162*>(&sW2h[h * C + c2]);
        float wx = __bfloat162float(wp.x), wy = __bfloat162float(wp.y);
        a0 = fmaf(hv.x, wx, a0); a1 = fmaf(hv.y, wx, a1);
        a2 = fmaf(hv.z, wx, a2); a3 = fmaf(hv.w, wx, a3);
        c0 = fmaf(hv.x, wy, c0); c1 = fmaf(hv.y, wy, c1);
        c2a = fmaf(hv.z, wy, c2a); c3 = fmaf(hv.w, wy, c3);
      }
      if (jbase + 0 < jt) { m0 = fmaxf(m0, a0); m1 = fmaxf(m1, c0); }
      if (jbase + 1 < jt) { m0 = fmaxf(m0, a1); m1 = fmaxf(m1, c1); }
      if (jbase + 2 < jt) { m0 = fmaxf(m0, a2); m1 = fmaxf(m1, c2a); }
      if (jbase + 3 < jt) { m0 = fmaxf(m0, a3); m1 = fmaxf(m1, c3); }
    }
    __syncthreads();
    sRed[sgi * C + c2]     = m0;
    sRed[sgi * C + c2 + 1] = m1;
    __syncthreads();
    if (tid < TPS) {
      int c = 2 * tid;
      float M0 = sRed[c], M1 = sRed[c + 1];
      #pragma unroll
      for (int s2 = 1; s2 < SG; ++s2) {
        M0 = fmaxf(M0, sRed[s2 * C + c]);
        M1 = fmaxf(M1, sRed[s2 * C + c + 1]);
      }
      float o0 = nn > 0 ? M0 + b2v[c]     : 0.f;
      float o1 = nn > 0 ? M1 + b2v[c + 1] : 0.f;
      float* orow = outb + (size_t)i * C;
      orow[c] = o0; orow[c + 1] = o1;
    }
    __syncthreads();
  }
}

// ------- mega: blocks 0-7 = FPS producer (prio 3); rest = persistent SA consumers -------
// Grid is exactly 256 blocks and dynamic LDS is >80 KiB, so at most ONE block fits per
// CU (160 KiB LDS pool) -> every block gets a dedicated CU; FPS runs uncontended.
template<int NF, int MF, int NPTF, int NS, int HS, int CS, int QB, int NC>
__global__ __launch_bounds__(512, 2) void mega_kernel(
    const float* __restrict__ fsrc, float* __restrict__ fdst, int* __restrict__ prog,
    const float* __restrict__ src, const float* __restrict__ g,
    const float* __restrict__ W2, const float* __restrict__ b1v,
    const float* __restrict__ W1p, const float* __restrict__ b2v,
    float r2, float* __restrict__ out) {
  constexpr int TT = 8 * (MF / QB);   // total sa tiles
  extern __shared__ __align__(16) char smem[];
  if (blockIdx.x < 8) {
    __builtin_amdgcn_s_setprio(3);  // FPS is the latency-critical serial chain
    fps_body<NF, MF, NPTF, 512>(fsrc + (size_t)blockIdx.x * NF * 3,
                                fdst + (size_t)blockIdx.x * MF * 3, smem,
                                prog + blockIdx.x);
    return;
  }
  const int cons = blockIdx.x - 8;
  for (int tt = cons; tt < TT; tt += NC) {   // ascending qt -> streams with producer
    const int qt = tt >> 3, b = tt & 7;
    sa_body<NS, HS, CS, QB, 512>(src + (size_t)b * NS * 3, g + (size_t)b * NS * HS,
                                 fdst + (size_t)b * MF * 3, W2, b1v, W1p, b2v, r2, MF,
                                 out + (size_t)b * MF * CS, qt, smem, prog + b);
  }
}

// LDS pad: > half of the 160 KiB pool -> hardware cannot co-schedule 2 blocks/CU.
#define MEGA_SMEM 86016

// ---------------- tail: copy p3 and synthesize batch ids into d_out ----------------
__global__ void tail_kernel(const float* __restrict__ p3, float* __restrict__ d_out) {
  int i = blockIdx.x * 256 + threadIdx.x;
  if (i < 8 * 512 * 3) d_out[524288 + i] = p3[i];
  if (i < 8 * 512)     d_out[536576 + i] = (float)(i >> 9);
}

extern "C" void kernel_launch(void* const* d_in, const int* in_sizes, int n_in,
                              void* d_out, int out_size, void* d_ws, size_t ws_size,
                              hipStream_t stream) {
  (void)in_sizes; (void)n_in; (void)out_size; (void)ws_size;
  const float* pos = (const float*)d_in[0];
  const float* w11 = (const float*)d_in[2];
  const float* b11 = (const float*)d_in[3];
  const float* w12 = (const float*)d_in[4];
  const float* b12 = (const float*)d_in[5];
  const float* w21 = (const float*)d_in[6];
  const float* b21 = (const float*)d_in[7];
  const float* w22 = (const float*)d_in[8];
  const float* b22 = (const float*)d_in[9];
  const float* w31 = (const float*)d_in[10];
  const float* b31 = (const float*)d_in[11];
  const float* w32 = (const float*)d_in[12];
  const float* b32 = (const float*)d_in[13];

  float* ws = (float*)d_ws;
  float* p1 = ws; ws += 8 * 2048 * 3;
  float* p2 = ws; ws += 8 * 512 * 3;
  float* p3 = ws; ws += 8 * 512 * 3;
  float* g1 = ws; ws += 8 * 4096 * 32;
  float* x1 = ws; ws += 8 * 2048 * 32;
  float* g2 = ws; ws += 8 * 2048 * 64;
  float* x2 = ws; ws += 8 * 512 * 64;
  float* g3 = ws; ws += 8 * 512 * 128;
  int* prog1 = (int*)ws; ws += 8;   // poison 0xAA.. is negative -> consumers spin
  int* prog2 = (int*)ws; ws += 8;
  int* prog3 = (int*)ws; ws += 8;
  float* x3 = (float*)d_out;

  // g1 first (independent of fps1)
  g_kernel<3, 32><<<dim3(8 * 4096 * 32 / 256), dim3(256), 0, stream>>>(pos, pos, w11, g1, 8 * 4096);

  // mega1: fps1 (pos -> p1) with sa1 streaming p1 rows (pos,g1,p1 -> x1)
  mega_kernel<4096, 2048, 8, 4096, 32, 32, 8, 248><<<dim3(256), dim3(512), MEGA_SMEM, stream>>>(
      pos, p1, prog1, pos, g1, w12, b11, w11 + 3 * 32, b12, 0.04f, x1);

  g_kernel<32, 64><<<dim3(8 * 2048 * 64 / 256), dim3(256), 0, stream>>>(x1, p1, w21, g2, 8 * 2048);

  // mega2: fps2 (p1 -> p2) with sa2 streaming p2 rows (p1,g2,p2 -> x2)
  mega_kernel<2048, 512, 4, 2048, 64, 64, 8, 248><<<dim3(256), dim3(512), MEGA_SMEM, stream>>>(
      p1, p2, prog2, p1, g2, w22, b21, w21 + 32 * 64, b22, 0.16f, x2);

  g_kernel<64, 128><<<dim3(8 * 512 * 128 / 256), dim3(256), 0, stream>>>(x2, p2, w31, g3, 8 * 512);

  // mega3: fps3 (p2 -> p3) with sa3 streaming p3 rows (p2,g3,p3 -> x3)
  mega_kernel<512, 512, 1, 512, 128, 128, 8, 248><<<dim3(256), dim3(512), MEGA_SMEM, stream>>>(
      p2, p3, prog3, p2, g3, w32, b31, w31 + 64 * 128, b32, 1.0f, x3);

  tail_kernel<<<dim3(48), dim3(256), 0, stream>>>(p3, (float*)d_out);
}

// Round 10
// 2250.930 us; speedup vs baseline: 1.5709x; 1.1539x over previous
//
#include <hip/hip_runtime.h>
#include <hip/hip_bf16.h>
#include <float.h>

typedef unsigned long long u64;

// ---------- exact-rounding helpers (match numpy fp32, no FMA contraction) ----------
static __device__ __forceinline__ float d2_rn(float ax, float ay, float az,
                                              float bx, float by, float bz) {
  float dx = __fsub_rn(ax, bx), dy = __fsub_rn(ay, by), dz = __fsub_rn(az, bz);
  return __fadd_rn(__fadd_rn(__fmul_rn(dx, dx), __fmul_rn(dy, dy)), __fmul_rn(dz, dz));
}

// merge two descending-sorted top-2 lists of packed keys -> top-2 in (a1,a2)
static __device__ __forceinline__ void merge2(u64& a1, u64& a2, u64 b1, u64 b2) {
  bool agt = a1 > b1;
  u64 m1 = agt ? a1 : b1;
  u64 lo = agt ? b1 : a1;
  u64 cs = agt ? a2 : b2;
  a1 = m1;
  a2 = lo > cs ? lo : cs;
}

static __device__ __forceinline__ u64 pack_key(float v, int i) {
  // nonneg float bits are monotone as uint; ~i gives first-index tie-break under max.
  if (v < 0.f) return 0ull;
  return ((u64)__float_as_uint(v) << 32) | (unsigned)(~i);
}

// DPP cross-lane move of a u64 (two 32-bit halves). bound_ctrl=1 -> invalid lanes read 0.
template<int CTRL>
static __device__ __forceinline__ u64 dpp_u64(u64 x) {
  unsigned lo = (unsigned)__builtin_amdgcn_update_dpp(0, (int)(unsigned)x, CTRL, 0xF, 0xF, true);
  unsigned hi = (unsigned)__builtin_amdgcn_update_dpp(0, (int)(unsigned)(x >> 32), CTRL, 0xF, 0xF, true);
  return ((u64)hi << 32) | lo;
}

template<int CTRL>
static __device__ __forceinline__ void merge_dpp(u64& a1, u64& a2) {
  u64 b1 = dpp_u64<CTRL>(a1);
  u64 b2 = dpp_u64<CTRL>(a2);
  merge2(a1, a2, b1, b2);
}

// Full-wave top-2 reduce at VALU latency; exact result lands in LANE 63.
static __device__ __forceinline__ void wave_top2_dpp(u64& a1, u64& a2) {
  merge_dpp<0xB1>(a1, a2);    // xor 1
  merge_dpp<0x4E>(a1, a2);    // xor 2
  merge_dpp<0x141>(a1, a2);   // row_half_mirror: xor 4
  merge_dpp<0x140>(a1, a2);   // row_mirror: xor 8
  merge_dpp<0x142>(a1, a2);   // row_bcast15
  merge_dpp<0x143>(a1, a2);   // row_bcast31; lane63 = full wave
}

// ---------------- FPS: 1 barrier/step, DPP top-2 argmax, top-2 speculation ----------------
template<int N, int M, int NPT, int T>
static __device__ void fps_body(const float* __restrict__ P, float* __restrict__ O,
                                char* smem) {
  constexpr int W = T / 64;
  static_assert(N == T * NPT, "layout");
  float* xs = (float*)smem;
  float* ys = xs + N;
  float* zs = ys + N;
  uint4* slots = (uint4*)(zs + N);   // [2][W]
  const int tid = threadIdx.x;
  const int lane = tid & 63, wv = tid >> 6;

  for (int j = tid; j < N; j += T) {
    xs[j] = P[3 * j]; ys[j] = P[3 * j + 1]; zs[j] = P[3 * j + 2];
  }
  __syncthreads();

  const float c0x = xs[0], c0y = ys[0], c0z = zs[0];
  if (tid == 0) { O[0] = c0x; O[1] = c0y; O[2] = c0z; }

  float md[NPT], px[NPT], py[NPT], pz[NPT];
  float v1 = -1.f, v2 = -1.f; int i1 = 0, i2 = 0;
  #pragma unroll
  for (int k = 0; k < NPT; ++k) {
    int j = tid + k * T;  // ascending j -> '>' keeps first index on ties
    px[k] = xs[j]; py[k] = ys[j]; pz[k] = zs[j];
    float m = d2_rn(px[k], py[k], pz[k], c0x, c0y, c0z);
    md[k] = m;
    if (m > v2) { if (m > v1) { v2=v1; i2=i1; v1=m; i1=j; } else { v2=m; i2=j; } }
  }
  // Pin the per-thread position copies into VGPRs. Without this the allocator
  // rematerializes px/py/pz as ds_read_b32 in the update loop (round-9 finding:
  // VGPR_Count=40 < the 32 regs the arrays need, i.e. 24 LDS reads/thread/round
  // ≈ 384 LDS-pipe cycles/round/CU — the dominant per-round cost). Opaque asm
  // makes remat impossible; values must stay register-resident.
  #pragma unroll
  for (int k = 0; k < NPT; ++k)
    asm volatile("" : "+v"(px[k]), "+v"(py[k]), "+v"(pz[k]));

  u64 a1 = pack_key(v1, i1), a2 = pack_key(v2, i2);
  wave_top2_dpp(a1, a2);
  if (lane == 63)
    slots[wv] = make_uint4((unsigned)a1, (unsigned)(a1 >> 32),
                           (unsigned)a2, (unsigned)(a2 >> 32));

  int t = 1, phase = 0;
  while (t < M) {
    __syncthreads();
    // ---- cross-wave merge: lane reads slot[lane&(W-1)]; 3 DPP levels -> global top-2
    uint4 s = slots[phase * W + (lane & (W - 1))];
    a1 = ((u64)s.y << 32) | s.x;
    a2 = ((u64)s.w << 32) | s.z;
    merge_dpp<0xB1>(a1, a2);   // xor 1
    merge_dpp<0x4E>(a1, a2);   // xor 2
    merge_dpp<0x141>(a1, a2);  // xor 4 (8 slots fully merged, uniform everywhere)

    const int j1 = (int)(~(unsigned)a1);
    const float c1x = xs[j1], c1y = ys[j1], c1z = zs[j1];
    const float v2f = __uint_as_float((unsigned)(a2 >> 32));

    bool hit = false;
    float c2x = 0.f, c2y = 0.f, c2z = 0.f;
    if (t + 1 < M && v2f > 0.f) {
      int j2 = (int)(~(unsigned)a2);
      c2x = xs[j2]; c2y = ys[j2]; c2z = zs[j2];
      float dd = d2_rn(c2x, c2y, c2z, c1x, c1y, c1z);
      hit = (dd >= v2f);   // then md'[j2]=v2 stays the exact (val,first-idx) max
    }

    if (tid == 0) {
      O[3 * t] = c1x; O[3 * t + 1] = c1y; O[3 * t + 2] = c1z;
      if (hit) { O[3 * t + 3] = c2x; O[3 * t + 4] = c2y; O[3 * t + 5] = c2z; }
    }

    v1 = -1.f; v2 = -1.f; i1 = 0; i2 = 0;
    if (hit) {
      #pragma unroll
      for (int k = 0; k < NPT; ++k) {
        float m = md[k];
        m = fminf(m, d2_rn(px[k], py[k], pz[k], c1x, c1y, c1z));
        m = fminf(m, d2_rn(px[k], py[k], pz[k], c2x, c2y, c2z));
        md[k] = m;
        int j = tid + k * T;
        if (m > v2) { if (m > v1) { v2=v1; i2=i1; v1=m; i1=j; } else { v2=m; i2=j; } }
      }
    } else {
      #pragma unroll
      for (int k = 0; k < NPT; ++k) {
        float m = fminf(md[k], d2_rn(px[k], py[k], pz[k], c1x, c1y, c1z));
        md[k] = m;
        int j = tid + k * T;
        if (m > v2) { if (m > v1) { v2=v1; i2=i1; v1=m; i1=j; } else { v2=m; i2=j; } }
      }
    }

    a1 = pack_key(v1, i1); a2 = pack_key(v2, i2);
    wave_top2_dpp(a1, a2);
    if (lane == 63)
      slots[(phase ^ 1) * W + wv] = make_uint4((unsigned)a1, (unsigned)(a1 >> 32),
                                               (unsigned)a2, (unsigned)(a2 >> 32));
    phase ^= 1;
    t += hit ? 2 : 1;
  }
}

template<int N, int M, int NPT>
__global__ __launch_bounds__(512, 2) void fps_kernel(const float* __restrict__ pos,
                                                     float* __restrict__ out) {
  __shared__ __align__(16) char smem[3 * N * 4 + 2 * 8 * 16];
  fps_body<N, M, NPT, 512>(pos + (size_t)blockIdx.x * N * 3,
                           out + (size_t)blockIdx.x * M * 3, smem);
}

// ------------- per-source g[j] = x_j @ W1x + pos_j @ W1p  (tiny GEMM) -------------
template<int C, int H>
__global__ void g_kernel(const float* __restrict__ x, const float* __restrict__ pos,
                         const float* __restrict__ W, float* __restrict__ g, int rows) {
  int idx = blockIdx.x * 256 + threadIdx.x;
  if (idx >= rows * H) return;
  int row = idx / H, h = idx - row * H;
  const float* xr = x + (size_t)row * C;
  const float* pr = pos + (size_t)row * 3;
  float acc = 0.f;
  for (int c = 0; c < C; ++c) acc = fmaf(xr[c], W[c * H + h], acc);
  #pragma unroll
  for (int c = 0; c < 3; ++c) acc = fmaf(pr[c], W[(C + c) * H + h], acc);
  g[idx] = acc;
}

// ---------------- SA layer body (templated on thread count T) ----------------
template<int N, int H, int C, int T>
constexpr int sa_smem_bytes() {
  constexpr int TPS = C / 2, SG = T / TPS, JT = SG * 4, STRIDE = JT + 4;
  constexpr int SCR = (SG * C > 512) ? SG * C : 512;
  return H * C * 2 + N * 4 + H * 4 + STRIDE * H * 4 + SCR * 4 + 64 * 4 + 8 * 4 + 8 * 4;
}

template<int N, int H, int C, int QB, int T>
static __device__ void sa_body(const float* __restrict__ srcb,  // [N,3]
                               const float* __restrict__ gb,    // [N,H]
                               const float* __restrict__ qposb, // [M,3]
                               const float* __restrict__ W2, const float* __restrict__ b1v,
                               const float* __restrict__ W1p, const float* __restrict__ b2v,
                               float r2, int M, float* __restrict__ outb, int qtile,
                               char* smem) {
  constexpr int TPS = C / 2;
  constexpr int SG  = T / TPS;
  constexpr int JT  = SG * 4;
  constexpr int STRIDE = JT + 4;
  constexpr int SCR = (SG * C > 512) ? SG * C : 512;
  const int tid = threadIdx.x;
  const int sgi = tid / TPS;
  const int c2 = 2 * (tid - sgi * TPS);

  __hip_bfloat16* sW2h = (__hip_bfloat16*)smem;          // H*C*2
  float* sD2  = (float*)(smem + H * C * 2);              // N
  float* sT   = sD2 + N;                                 // H
  float* sHj  = sT + H;                                  // STRIDE*H (16B aligned)
  float* sScr = sHj + STRIDE * H;                        // SCR
  int*   sNbr = (int*)(sScr + SCR);                      // 64
  int*   sWS  = sNbr + 64;                               // 8
  int*   sIv  = sWS + 8;   // [0]=Cnt [1]=Nn [2]=Nc [3]=Bin [4]=Before [5]=TauI
  float* sFv  = (float*)(sIv + 6);  // [0]=TauV

  int*   sHist  = (int*)sScr;
  float* sCand  = sScr + 256;
  int*   sCandI = (int*)(sScr + 320);
  float* sRed   = sScr;

  for (int e = tid; e < H * C; e += T) sW2h[e] = __float2bfloat16(W2[e]);

  for (int qi = 0; qi < QB; ++qi) {
    const int i = qtile * QB + qi;
    const float* qp = qposb + (size_t)i * 3;
    const float qx = qp[0], qy = qp[1], qz = qp[2];
    const float qq = __fadd_rn(__fadd_rn(__fmul_rn(qx, qx), __fmul_rn(qy, qy)),
                               __fmul_rn(qz, qz));
    if (tid < H)
      sT[tid] = fmaf(qx, W1p[tid], fmaf(qy, W1p[H + tid], fmaf(qz, W1p[2 * H + tid], -b1v[tid])));
    if (tid == 0) { sIv[0] = 0; sIv[1] = 0; sIv[2] = 0; }
    if (tid < 256) sHist[tid] = 0;
    __syncthreads();

    // ---- pass 1: d2 (reference formula, exact rounding) + in-radius count ----
    int lc = 0;
    for (int j = tid; j < N; j += T) {
      float sx = srcb[3 * j], sy = srcb[3 * j + 1], sz = srcb[3 * j + 2];
      float ss  = __fadd_rn(__fadd_rn(__fmul_rn(sx, sx), __fmul_rn(sy, sy)), __fmul_rn(sz, sz));
      float dot = __fadd_rn(__fadd_rn(__fmul_rn(qx, sx), __fmul_rn(qy, sy)), __fmul_rn(qz, sz));
      float d2  = __fsub_rn(__fadd_rn(qq, ss), __fmul_rn(2.0f, dot));
      sD2[j] = d2;
      lc += (d2 <= r2) ? 1 : 0;
    }
    #pragma unroll
    for (int off = 32; off > 0; off >>= 1) lc += __shfl_xor(lc, off, 64);
    if ((tid & 63) == 0) atomicAdd(&sIv[0], lc);
    __syncthreads();
    const int cnt = sIv[0];

    // ---- exact rank-64 threshold (lexicographic (d2, idx), matches lax.top_k) ----
    float tauv; int taui;
    if (cnt <= 64) {
      tauv = r2; taui = 0x7fffffff;
    } else {
      const float scale = 256.0f / r2;
      for (int j = tid; j < N; j += T) {
        float d2 = sD2[j];
        if (d2 <= r2) {
          int bin = (int)(d2 * scale);
          bin = bin < 0 ? 0 : (bin > 255 ? 255 : bin);
          atomicAdd(&sHist[bin], 1);
        }
      }
      __syncthreads();
      int cbin = (tid < 256) ? sHist[tid] : 0;
      int lane = tid & 63, wvi = tid >> 6;
      int v = cbin;
      #pragma unroll
      for (int off = 1; off < 64; off <<= 1) {
        int o = __shfl_up(v, off, 64);
        if (lane >= off) v += o;
      }
      if (lane == 63) sWS[wvi] = v;
      __syncthreads();
      int wadd = 0;
      for (int w = 0; w < wvi; ++w) wadd += sWS[w];
      int incl = v + wadd, excl = incl - cbin;
      if (tid < 256 && excl < 64 && incl >= 64) { sIv[3] = tid; sIv[4] = excl; }
      __syncthreads();
      const int bstar = sIv[3];
      const int kneed = 64 - sIv[4];
      for (int j = tid; j < N; j += T) {
        float d2 = sD2[j];
        if (d2 <= r2) {
          int bin = (int)(d2 * scale);
          bin = bin < 0 ? 0 : (bin > 255 ? 255 : bin);
          if (bin == bstar) {
            int p = atomicAdd(&sIv[2], 1);
            if (p < 64) { sCand[p] = d2; sCandI[p] = j; }
          }
        }
      }
      __syncthreads();
      if (tid == 0) {
        int nc = sIv[2] < 64 ? sIv[2] : 64;
        for (int a = 1; a < nc; ++a) {
          float dv = sCand[a]; int di = sCandI[a];
          int p = a - 1;
          while (p >= 0 && (sCand[p] > dv || (sCand[p] == dv && sCandI[p] > di))) {
            sCand[p + 1] = sCand[p]; sCandI[p + 1] = sCandI[p]; --p;
          }
          sCand[p + 1] = dv; sCandI[p + 1] = di;
        }
        int kk = (kneed < nc ? kneed : nc) - 1; if (kk < 0) kk = 0;
        sFv[0] = sCand[kk]; sIv[5] = sCandI[kk];
      }
      __syncthreads();
      tauv = sFv[0]; taui = sIv[5];
    }

    // ---- compact neighbor list (set membership only; order irrelevant for max) ----
    for (int j = tid; j < N; j += T) {
      float d2 = sD2[j];
      if (d2 < tauv || (d2 == tauv && j <= taui)) {
        int p = atomicAdd(&sIv[1], 1);
        if (p < 64) sNbr[p] = j;
      }
    }
    __syncthreads();
    const int nn = sIv[1] < 64 ? sIv[1] : 64;

    // ---- MLP: h = ReLU(g[j]-t[i]);  out_c = max_j (h @ W2)_c + b2_c ----
    float m0 = -FLT_MAX, m1 = -FLT_MAX;
    for (int t0 = 0; t0 < nn; t0 += JT) {
      int jt = nn - t0; if (jt > JT) jt = JT;
      __syncthreads();
      for (int e = tid; e < JT * H; e += T) {
        int jj = e / H, h = e - jj * H;
        float hv = 0.f;
        if (jj < jt) {
          int j = sNbr[t0 + jj];
          hv = gb[(size_t)j * H + h] - sT[h];
          hv = hv > 0.f ? hv : 0.f;
        }
        sHj[h * STRIDE + jj] = hv;
      }
      __syncthreads();
      float a0 = 0, a1 = 0, a2 = 0, a3 = 0, c0 = 0, c1 = 0, c2a = 0, c3 = 0;
      const int jbase = sgi * 4;
      for (int h = 0; h < H; ++h) {
        float4 hv = *reinterpret_cast<const float4*>(&sHj[h * STRIDE + jbase]);
        __hip_bfloat162 wp = *reinterpret_cast<const __hip_bfloat162*>(&sW2h[h * C + c2]);
        float wx = __bfloat162float(wp.x), wy = __bfloat162float(wp.y);
        a0 = fmaf(hv.x, wx, a0); a1 = fmaf(hv.y, wx, a1);
        a2 = fmaf(hv.z, wx, a2); a3 = fmaf(hv.w, wx, a3);
        c0 = fmaf(hv.x, wy, c0); c1 = fmaf(hv.y, wy, c1);
        c2a = fmaf(hv.z, wy, c2a); c3 = fmaf(hv.w, wy, c3);
      }
      if (jbase + 0 < jt) { m0 = fmaxf(m0, a0); m1 = fmaxf(m1, c0); }
      if (jbase + 1 < jt) { m0 = fmaxf(m0, a1); m1 = fmaxf(m1, c1); }
      if (jbase + 2 < jt) { m0 = fmaxf(m0, a2); m1 = fmaxf(m1, c2a); }
      if (jbase + 3 < jt) { m0 = fmaxf(m0, a3); m1 = fmaxf(m1, c3); }
    }
    __syncthreads();
    sRed[sgi * C + c2]     = m0;
    sRed[sgi * C + c2 + 1] = m1;
    __syncthreads();
    if (tid < TPS) {
      int c = 2 * tid;
      float M0 = sRed[c], M1 = sRed[c + 1];
      #pragma unroll
      for (int s2 = 1; s2 < SG; ++s2) {
        M0 = fmaxf(M0, sRed[s2 * C + c]);
        M1 = fmaxf(M1, sRed[s2 * C + c + 1]);
      }
      float o0 = nn > 0 ? M0 + b2v[c]     : 0.f;
      float o1 = nn > 0 ? M1 + b2v[c + 1] : 0.f;
      float* orow = outb + (size_t)i * C;
      orow[c] = o0; orow[c + 1] = o1;
    }
    __syncthreads();
  }
}

template<int N, int H, int C, int QB>
__global__ __launch_bounds__(256) void sa_kernel(
    const float* __restrict__ src, const float* __restrict__ g,
    const float* __restrict__ qpos, const float* __restrict__ W2,
    const float* __restrict__ b1v, const float* __restrict__ W1p,
    const float* __restrict__ b2v, float r2, int M, float* __restrict__ out) {
  __shared__ __align__(16) char smem[sa_smem_bytes<N, H, C, 256>()];
  const int b = blockIdx.y;
  sa_body<N, H, C, QB, 256>(src + (size_t)b * N * 3, g + (size_t)b * N * H,
                            qpos + (size_t)b * M * 3, W2, b1v, W1p, b2v, r2, M,
                            out + (size_t)b * M * C, blockIdx.x, smem);
}

// ------- fused: blocks 0-7 run FPS (next layer's sampling), rest run SA (this layer) -------
template<int NF, int MF, int NPTF, int NS, int HS, int CS, int QB, int SAB>
__global__ __launch_bounds__(512, 2) void fused_kernel(
    const float* __restrict__ fsrc, float* __restrict__ fdst,
    const float* __restrict__ src, const float* __restrict__ g,
    const float* __restrict__ qpos, const float* __restrict__ W2,
    const float* __restrict__ b1v, const float* __restrict__ W1p,
    const float* __restrict__ b2v, float r2, int M, float* __restrict__ out) {
  constexpr int FPS_BYTES = 3 * NF * 4 + 2 * 8 * 16;
  constexpr int SA_BYTES  = sa_smem_bytes<NS, HS, CS, 512>();
  constexpr int SMEM = FPS_BYTES > SA_BYTES ? FPS_BYTES : SA_BYTES;
  __shared__ __align__(16) char smem[SMEM];
  if (blockIdx.x < 8) {
    __builtin_amdgcn_s_setprio(3);  // FPS is the latency-critical serial chain
    fps_body<NF, MF, NPTF, 512>(fsrc + (size_t)blockIdx.x * NF * 3,
                                fdst + (size_t)blockIdx.x * MF * 3, smem);
    return;
  }
  const int bi = blockIdx.x - 8;
  const int qt = bi % SAB;
  const int b  = bi / SAB;
  sa_body<NS, HS, CS, QB, 512>(src + (size_t)b * NS * 3, g + (size_t)b * NS * HS,
                               qpos + (size_t)b * M * 3, W2, b1v, W1p, b2v, r2, M,
                               out + (size_t)b * M * CS, qt, smem);
}

// ---------------- tail: copy p3 and synthesize batch ids into d_out ----------------
__global__ void tail_kernel(const float* __restrict__ p3, float* __restrict__ d_out) {
  int i = blockIdx.x * 256 + threadIdx.x;
  if (i < 8 * 512 * 3) d_out[524288 + i] = p3[i];
  if (i < 8 * 512)     d_out[536576 + i] = (float)(i >> 9);
}

extern "C" void kernel_launch(void* const* d_in, const int* in_sizes, int n_in,
                              void* d_out, int out_size, void* d_ws, size_t ws_size,
                              hipStream_t stream) {
  (void)in_sizes; (void)n_in; (void)out_size; (void)ws_size;
  const float* pos = (const float*)d_in[0];
  const float* w11 = (const float*)d_in[2];
  const float* b11 = (const float*)d_in[3];
  const float* w12 = (const float*)d_in[4];
  const float* b12 = (const float*)d_in[5];
  const float* w21 = (const float*)d_in[6];
  const float* b21 = (const float*)d_in[7];
  const float* w22 = (const float*)d_in[8];
  const float* b22 = (const float*)d_in[9];
  const float* w31 = (const float*)d_in[10];
  const float* b31 = (const float*)d_in[11];
  const float* w32 = (const float*)d_in[12];
  const float* b32 = (const float*)d_in[13];

  float* ws = (float*)d_ws;
  float* p1 = ws; ws += 8 * 2048 * 3;
  float* p2 = ws; ws += 8 * 512 * 3;
  float* p3 = ws; ws += 8 * 512 * 3;
  float* g1 = ws; ws += 8 * 4096 * 32;
  float* x1 = ws; ws += 8 * 2048 * 32;
  float* g2 = ws; ws += 8 * 2048 * 64;
  float* x2 = ws; ws += 8 * 512 * 64;
  float* g3 = ws; ws += 8 * 512 * 128;
  float* x3 = (float*)d_out;

  // layer 1: g1 (tiny, independent), then FPS1 (the long serial chain)
  g_kernel<3, 32><<<dim3(8 * 4096 * 32 / 256), dim3(256), 0, stream>>>(pos, pos, w11, g1, 8 * 4096);
  fps_kernel<4096, 2048, 8><<<dim3(8), dim3(512), 0, stream>>>(pos, p1);

  // fused A: fps2 (p1->p2) overlapped with sa1 (pos,g1,p1 -> x1); SAB = 2048/8 = 256
  fused_kernel<2048, 512, 4, 4096, 32, 32, 8, 256><<<dim3(8 + 8 * 256), dim3(512), 0, stream>>>(
      p1, p2, pos, g1, p1, w12, b11, w11 + 3 * 32, b12, 0.04f, 2048, x1);

  g_kernel<32, 64><<<dim3(8 * 2048 * 64 / 256), dim3(256), 0, stream>>>(x1, p1, w21, g2, 8 * 2048);

  // fused B: fps3 (p2->p3) overlapped with sa2 (p1,g2,p2 -> x2); SAB = 512/8 = 64
  fused_kernel<512, 512, 1, 2048, 64, 64, 8, 64><<<dim3(8 + 8 * 64), dim3(512), 0, stream>>>(
      p2, p3, p1, g2, p2, w22, b21, w21 + 32 * 64, b22, 0.16f, 512, x2);

  g_kernel<64, 128><<<dim3(8 * 512 * 128 / 256), dim3(256), 0, stream>>>(x2, p2, w31, g3, 8 * 512);

  sa_kernel<512, 128, 128, 8><<<dim3(64, 8), dim3(256), 0, stream>>>(
      p2, g3, p3, w32, b31, w31 + 64 * 128, b32, 1.0f, 512, x3);

  tail_kernel<<<dim3(48), dim3(256), 0, stream>>>(p3, (float*)d_out);
}

// Round 11
// 2184.710 us; speedup vs baseline: 1.6185x; 1.0303x over previous
//
#include <hip/hip_runtime.h>
#include <hip/hip_bf16.h>
#include <float.h>

typedef unsigned long long u64;

// ---------- exact-rounding helpers (match numpy fp32, no FMA contraction) ----------
static __device__ __forceinline__ float d2_rn(float ax, float ay, float az,
                                              float bx, float by, float bz) {
  float dx = __fsub_rn(ax, bx), dy = __fsub_rn(ay, by), dz = __fsub_rn(az, bz);
  return __fadd_rn(__fadd_rn(__fmul_rn(dx, dx), __fmul_rn(dy, dy)), __fmul_rn(dz, dz));
}

// ---------------- DPP primitives (float value reduce + int min-index reduce) ----------------
template<int CTRL>
static __device__ __forceinline__ float dpp_f32(float x) {
  // bound_ctrl=1 -> invalid lanes read 0.0f; all md values >= 0 so max/min stays safe
  return __int_as_float(__builtin_amdgcn_update_dpp(0, __float_as_int(x), CTRL, 0xF, 0xF, true));
}

template<int CTRL>
static __device__ __forceinline__ int dpp_min_i32(int x) {
  // old = INT_MAX, bound_ctrl=0 -> invalid lanes read INT_MAX (identity for min)
  int b = __builtin_amdgcn_update_dpp(0x7fffffff, x, CTRL, 0xF, 0xF, false);
  return x < b ? x : b;
}

// merge two top-2 VALUE lists held in (v1,v2) and their CTRL-shifted copies
template<int CTRL>
static __device__ __forceinline__ void top2_step(float& v1, float& v2) {
  float b1 = dpp_f32<CTRL>(v1);
  float b2 = dpp_f32<CTRL>(v2);
  float m1 = fmaxf(v1, b1);
  float lo = fminf(v1, b1);
  v2 = fmaxf(lo, fmaxf(v2, b2));
  v1 = m1;
}

// wave(64) top-2 values; exact result lands in lane 63
static __device__ __forceinline__ void wave_top2_vals(float& v1, float& v2) {
  top2_step<0xB1>(v1, v2);   // xor 1
  top2_step<0x4E>(v1, v2);   // xor 2
  top2_step<0x141>(v1, v2);  // row_half_mirror: xor 4
  top2_step<0x140>(v1, v2);  // row_mirror: xor 8
  top2_step<0x142>(v1, v2);  // row_bcast15
  top2_step<0x143>(v1, v2);  // row_bcast31; lane 63 = full wave
}

// 16-lane top-2 values; correct in lanes 0-15 (patterns stay within 16-lane groups)
static __device__ __forceinline__ void pool_top2_vals(float& v1, float& v2) {
  top2_step<0xB1>(v1, v2);
  top2_step<0x4E>(v1, v2);
  top2_step<0x141>(v1, v2);
  top2_step<0x140>(v1, v2);
}

static __device__ __forceinline__ int wave_min_idx(int c) {
  c = dpp_min_i32<0xB1>(c);  c = dpp_min_i32<0x4E>(c);
  c = dpp_min_i32<0x141>(c); c = dpp_min_i32<0x140>(c);
  c = dpp_min_i32<0x142>(c); c = dpp_min_i32<0x143>(c);
  return __builtin_amdgcn_readlane(c, 63);
}

static __device__ __forceinline__ int pool_min_idx(int c) {
  c = dpp_min_i32<0xB1>(c);  c = dpp_min_i32<0x4E>(c);
  c = dpp_min_i32<0x141>(c); c = dpp_min_i32<0x140>(c);
  return __builtin_amdgcn_readfirstlane(c);
}

static __device__ __forceinline__ float readlane_f(float x, int l) {
  return __int_as_float(__builtin_amdgcn_readlane(__float_as_int(x), l));
}

// Recover indices of the wave top-2 given per-lane exact (lv1,li1,lv2,li2) and the
// wave top-2 VALUES (s1,s2). Exact (value desc, index asc) semantics:
// common path = unique-max ballot + readlane; tie path = min-index DPP reduce.
static __device__ __forceinline__ void wave_recover_idx(float lv1, int li1, float lv2, int li2,
                                                        float s1, float s2, int lane,
                                                        int& i1g, int& i2g) {
  u64 b1 = __ballot(lv1 == s1);
  int lw;
  if (__popcll(b1) == 1) {
    lw = __ffsll(b1) - 1;
    i1g = __builtin_amdgcn_readlane(li1, lw);
  } else {
    i1g = wave_min_idx(lv1 == s1 ? li1 : 0x7fffffff);
    lw = __ffsll(__ballot(lv1 == s1 && li1 == i1g)) - 1;
  }
  float wlv = (lane == lw) ? lv2 : lv1;   // winner lane exposes its #2 instead
  int   wli = (lane == lw) ? li2 : li1;
  u64 b2 = __ballot(wlv == s2);
  if (__popcll(b2) == 1) {
    i2g = __builtin_amdgcn_readlane(wli, __ffsll(b2) - 1);
  } else {
    i2g = wave_min_idx(wlv == s2 ? wli : 0x7fffffff);
  }
}

// ---------------- FPS: 1 barrier/step, value-DPP top-2 argmax, top-2 speculation ----------------
template<int N, int M, int NPT, int T>
static __device__ void fps_body(const float* __restrict__ P, float* __restrict__ O,
                                char* smem) {
  constexpr int W = T / 64;
  static_assert(N == T * NPT, "layout");
  float4* pq = (float4*)smem;            // [N] interleaved coords (x,y,z,0)
  uint4* slots = (uint4*)(pq + N);       // [2][W]: (v1,i1,v2,i2)
  const int tid = threadIdx.x;
  const int lane = tid & 63, wv = tid >> 6;

  for (int j = tid; j < N; j += T)
    pq[j] = make_float4(P[3 * j], P[3 * j + 1], P[3 * j + 2], 0.f);
  __syncthreads();

  const float4 c0 = pq[0];
  if (tid == 0) { O[0] = c0.x; O[1] = c0.y; O[2] = c0.z; }

  float md[NPT], px[NPT], py[NPT], pz[NPT];
  float v1 = -1.f, v2 = -1.f; int i1 = 0, i2 = 0;
  #pragma unroll
  for (int k = 0; k < NPT; ++k) {
    int j = tid + k * T;  // ascending j -> strict '>' keeps first index on ties
    float4 p = pq[j];
    px[k] = p.x; py[k] = p.y; pz[k] = p.z;
    float m = d2_rn(p.x, p.y, p.z, c0.x, c0.y, c0.z);
    md[k] = m;
    if (m > v2) { if (m > v1) { v2=v1; i2=i1; v1=m; i1=j; } else { v2=m; i2=j; } }
  }

  {
    float r1 = v1, r2 = v2;
    wave_top2_vals(r1, r2);
    float s1 = readlane_f(r1, 63), s2 = readlane_f(r2, 63);
    int i1g, i2g;
    wave_recover_idx(v1, i1, v2, i2, s1, s2, lane, i1g, i2g);
    if (lane == 0)
      slots[wv] = make_uint4(__float_as_uint(s1), (unsigned)i1g,
                             __float_as_uint(s2), (unsigned)i2g);
  }

  int t = 1, phase = 0;
  while (t < M) {
    __syncthreads();
    // ---- pool merge: 16 lanes hold the 8 waves' (v1),(v2); 4 DPP levels + recovery ----
    uint4 sp = slots[phase * W + (lane & (W - 1))];
    float pv; int pidx;
    if (lane & 8) { pv = __uint_as_float(sp.z); pidx = (int)sp.w; }
    else          { pv = __uint_as_float(sp.x); pidx = (int)sp.y; }
    const bool inp = lane < 16;
    if (!inp) { pv = -1.0f; pidx = 0x7fffffff; }
    float r1 = pv, r2 = -1.0f;
    pool_top2_vals(r1, r2);
    const float s1v = __int_as_float(__builtin_amdgcn_readfirstlane(__float_as_int(r1)));
    const float s2v = __int_as_float(__builtin_amdgcn_readfirstlane(__float_as_int(r2)));
    u64 b1 = __ballot(inp && pv == s1v);
    int lw, j1;
    if (__popcll(b1) == 1) {
      lw = __ffsll(b1) - 1;
      j1 = __builtin_amdgcn_readlane(pidx, lw);
    } else {
      j1 = pool_min_idx((inp && pv == s1v) ? pidx : 0x7fffffff);
      lw = __ffsll(__ballot(inp && pv == s1v && pidx == j1)) - 1;
    }
    float pw = (lane == lw) ? -1.0f : pv;
    int j2 = 0;
    u64 b2 = __ballot(inp && pw == s2v);
    if (__popcll(b2) == 1) j2 = __builtin_amdgcn_readlane(pidx, __ffsll(b2) - 1);
    else if (b2)           j2 = pool_min_idx((inp && pw == s2v) ? pidx : 0x7fffffff);

    const float4 c1 = pq[j1];
    const float v2f = s2v;

    bool hit = false;
    float4 c2 = make_float4(0.f, 0.f, 0.f, 0.f);
    if (t + 1 < M && v2f > 0.f) {
      c2 = pq[j2];
      float dd = d2_rn(c2.x, c2.y, c2.z, c1.x, c1.y, c1.z);
      hit = (dd >= v2f);   // then md'[j2]=v2f stays the exact (val,first-idx) max
    }

    if (tid == 0) {
      O[3 * t] = c1.x; O[3 * t + 1] = c1.y; O[3 * t + 2] = c1.z;
      if (hit) { O[3 * t + 3] = c2.x; O[3 * t + 4] = c2.y; O[3 * t + 5] = c2.z; }
    }

    v1 = -1.f; v2 = -1.f; i1 = 0; i2 = 0;
    if (hit) {
      #pragma unroll
      for (int k = 0; k < NPT; ++k) {
        float m = md[k];
        m = fminf(m, d2_rn(px[k], py[k], pz[k], c1.x, c1.y, c1.z));
        m = fminf(m, d2_rn(px[k], py[k], pz[k], c2.x, c2.y, c2.z));
        md[k] = m;
        int j = tid + k * T;
        if (m > v2) { if (m > v1) { v2=v1; i2=i1; v1=m; i1=j; } else { v2=m; i2=j; } }
      }
    } else {
      #pragma unroll
      for (int k = 0; k < NPT; ++k) {
        float m = fminf(md[k], d2_rn(px[k], py[k], pz[k], c1.x, c1.y, c1.z));
        md[k] = m;
        int j = tid + k * T;
        if (m > v2) { if (m > v1) { v2=v1; i2=i1; v1=m; i1=j; } else { v2=m; i2=j; } }
      }
    }

    {
      float r1b = v1, r2b = v2;
      wave_top2_vals(r1b, r2b);
      float s1 = readlane_f(r1b, 63), s2 = readlane_f(r2b, 63);
      int i1g, i2g;
      wave_recover_idx(v1, i1, v2, i2, s1, s2, lane, i1g, i2g);
      if (lane == 0)
        slots[(phase ^ 1) * W + wv] = make_uint4(__float_as_uint(s1), (unsigned)i1g,
                                                 __float_as_uint(s2), (unsigned)i2g);
    }
    phase ^= 1;
    t += hit ? 2 : 1;
  }
}

template<int N, int M, int NPT>
__global__ __launch_bounds__(512, 2) void fps_kernel(const float* __restrict__ pos,
                                                     float* __restrict__ out) {
  __shared__ __align__(16) char smem[16 * N + 2 * 8 * 16];
  fps_body<N, M, NPT, 512>(pos + (size_t)blockIdx.x * N * 3,
                           out + (size_t)blockIdx.x * M * 3, smem);
}

// ------------- per-source g[j] = x_j @ W1x + pos_j @ W1p  (tiny GEMM) -------------
template<int C, int H>
__global__ void g_kernel(const float* __restrict__ x, const float* __restrict__ pos,
                         const float* __restrict__ W, float* __restrict__ g, int rows) {
  int idx = blockIdx.x * 256 + threadIdx.x;
  if (idx >= rows * H) return;
  int row = idx / H, h = idx - row * H;
  const float* xr = x + (size_t)row * C;
  const float* pr = pos + (size_t)row * 3;
  float acc = 0.f;
  for (int c = 0; c < C; ++c) acc = fmaf(xr[c], W[c * H + h], acc);
  #pragma unroll
  for (int c = 0; c < 3; ++c) acc = fmaf(pr[c], W[(C + c) * H + h], acc);
  g[idx] = acc;
}

// ---------------- SA layer body (templated on thread count T) ----------------
template<int N, int H, int C, int T>
constexpr int sa_smem_bytes() {
  constexpr int TPS = C / 2, SG = T / TPS, JT = SG * 4, STRIDE = JT + 4;
  constexpr int SCR = (SG * C > 512) ? SG * C : 512;
  return H * C * 2 + N * 4 + H * 4 + STRIDE * H * 4 + SCR * 4 + 64 * 4 + 8 * 4 + 8 * 4;
}

template<int N, int H, int C, int QB, int T>
static __device__ void sa_body(const float* __restrict__ srcb,  // [N,3]
                               const float* __restrict__ gb,    // [N,H]
                               const float* __restrict__ qposb, // [M,3]
                               const float* __restrict__ W2, const float* __restrict__ b1v,
                               const float* __restrict__ W1p, const float* __restrict__ b2v,
                               float r2, int M, float* __restrict__ outb, int qtile,
                               char* smem) {
  constexpr int TPS = C / 2;
  constexpr int SG  = T / TPS;
  constexpr int JT  = SG * 4;
  constexpr int STRIDE = JT + 4;
  constexpr int SCR = (SG * C > 512) ? SG * C : 512;
  const int tid = threadIdx.x;
  const int sgi = tid / TPS;
  const int c2 = 2 * (tid - sgi * TPS);

  __hip_bfloat16* sW2h = (__hip_bfloat16*)smem;          // H*C*2
  float* sD2  = (float*)(smem + H * C * 2);              // N
  float* sT   = sD2 + N;                                 // H
  float* sHj  = sT + H;                                  // STRIDE*H (16B aligned)
  float* sScr = sHj + STRIDE * H;                        // SCR
  int*   sNbr = (int*)(sScr + SCR);                      // 64
  int*   sWS  = sNbr + 64;                               // 8
  int*   sIv  = sWS + 8;   // [0]=Cnt [1]=Nn [2]=Nc [3]=Bin [4]=Before [5]=TauI
  float* sFv  = (float*)(sIv + 6);  // [0]=TauV

  int*   sHist  = (int*)sScr;
  float* sCand  = sScr + 256;
  int*   sCandI = (int*)(sScr + 320);
  float* sRed   = sScr;

  for (int e = tid; e < H * C; e += T) sW2h[e] = __float2bfloat16(W2[e]);

  for (int qi = 0; qi < QB; ++qi) {
    const int i = qtile * QB + qi;
    const float* qp = qposb + (size_t)i * 3;
    const float qx = qp[0], qy = qp[1], qz = qp[2];
    const float qq = __fadd_rn(__fadd_rn(__fmul_rn(qx, qx), __fmul_rn(qy, qy)),
                               __fmul_rn(qz, qz));
    if (tid < H)
      sT[tid] = fmaf(qx, W1p[tid], fmaf(qy, W1p[H + tid], fmaf(qz, W1p[2 * H + tid], -b1v[tid])));
    if (tid == 0) { sIv[0] = 0; sIv[1] = 0; sIv[2] = 0; }
    if (tid < 256) sHist[tid] = 0;
    __syncthreads();

    // ---- pass 1: d2 (reference formula, exact rounding) + in-radius count ----
    int lc = 0;
    for (int j = tid; j < N; j += T) {
      float sx = srcb[3 * j], sy = srcb[3 * j + 1], sz = srcb[3 * j + 2];
      float ss  = __fadd_rn(__fadd_rn(__fmul_rn(sx, sx), __fmul_rn(sy, sy)), __fmul_rn(sz, sz));
      float dot = __fadd_rn(__fadd_rn(__fmul_rn(qx, sx), __fmul_rn(qy, sy)), __fmul_rn(qz, sz));
      float d2  = __fsub_rn(__fadd_rn(qq, ss), __fmul_rn(2.0f, dot));
      sD2[j] = d2;
      lc += (d2 <= r2) ? 1 : 0;
    }
    #pragma unroll
    for (int off = 32; off > 0; off >>= 1) lc += __shfl_xor(lc, off, 64);
    if ((tid & 63) == 0) atomicAdd(&sIv[0], lc);
    __syncthreads();
    const int cnt = sIv[0];

    // ---- exact rank-64 threshold (lexicographic (d2, idx), matches lax.top_k) ----
    float tauv; int taui;
    if (cnt <= 64) {
      tauv = r2; taui = 0x7fffffff;
    } else {
      const float scale = 256.0f / r2;
      for (int j = tid; j < N; j += T) {
        float d2 = sD2[j];
        if (d2 <= r2) {
          int bin = (int)(d2 * scale);
          bin = bin < 0 ? 0 : (bin > 255 ? 255 : bin);
          atomicAdd(&sHist[bin], 1);
        }
      }
      __syncthreads();
      int cbin = (tid < 256) ? sHist[tid] : 0;
      int lane = tid & 63, wvi = tid >> 6;
      int v = cbin;
      #pragma unroll
      for (int off = 1; off < 64; off <<= 1) {
        int o = __shfl_up(v, off, 64);
        if (lane >= off) v += o;
      }
      if (lane == 63) sWS[wvi] = v;
      __syncthreads();
      int wadd = 0;
      for (int w = 0; w < wvi; ++w) wadd += sWS[w];
      int incl = v + wadd, excl = incl - cbin;
      if (tid < 256 && excl < 64 && incl >= 64) { sIv[3] = tid; sIv[4] = excl; }
      __syncthreads();
      const int bstar = sIv[3];
      const int kneed = 64 - sIv[4];
      for (int j = tid; j < N; j += T) {
        float d2 = sD2[j];
        if (d2 <= r2) {
          int bin = (int)(d2 * scale);
          bin = bin < 0 ? 0 : (bin > 255 ? 255 : bin);
          if (bin == bstar) {
            int p = atomicAdd(&sIv[2], 1);
            if (p < 64) { sCand[p] = d2; sCandI[p] = j; }
          }
        }
      }
      __syncthreads();
      if (tid == 0) {
        int nc = sIv[2] < 64 ? sIv[2] : 64;
        for (int a = 1; a < nc; ++a) {
          float dv = sCand[a]; int di = sCandI[a];
          int p = a - 1;
          while (p >= 0 && (sCand[p] > dv || (sCand[p] == dv && sCandI[p] > di))) {
            sCand[p + 1] = sCand[p]; sCandI[p + 1] = sCandI[p]; --p;
          }
          sCand[p + 1] = dv; sCandI[p + 1] = di;
        }
        int kk = (kneed < nc ? kneed : nc) - 1; if (kk < 0) kk = 0;
        sFv[0] = sCand[kk]; sIv[5] = sCandI[kk];
      }
      __syncthreads();
      tauv = sFv[0]; taui = sIv[5];
    }

    // ---- compact neighbor list (set membership only; order irrelevant for max) ----
    for (int j = tid; j < N; j += T) {
      float d2 = sD2[j];
      if (d2 < tauv || (d2 == tauv && j <= taui)) {
        int p = atomicAdd(&sIv[1], 1);
        if (p < 64) sNbr[p] = j;
      }
    }
    __syncthreads();
    const int nn = sIv[1] < 64 ? sIv[1] : 64;

    // ---- MLP: h = ReLU(g[j]-t[i]);  out_c = max_j (h @ W2)_c + b2_c ----
    float m0 = -FLT_MAX, m1 = -FLT_MAX;
    for (int t0 = 0; t0 < nn; t0 += JT) {
      int jt = nn - t0; if (jt > JT) jt = JT;
      __syncthreads();
      for (int e = tid; e < JT * H; e += T) {
        int jj = e / H, h = e - jj * H;
        float hv = 0.f;
        if (jj < jt) {
          int j = sNbr[t0 + jj];
          hv = gb[(size_t)j * H + h] - sT[h];
          hv = hv > 0.f ? hv : 0.f;
        }
        sHj[h * STRIDE + jj] = hv;
      }
      __syncthreads();
      float a0 = 0, a1 = 0, a2 = 0, a3 = 0, c0 = 0, c1 = 0, c2a = 0, c3 = 0;
      const int jbase = sgi * 4;
      for (int h = 0; h < H; ++h) {
        float4 hv = *reinterpret_cast<const float4*>(&sHj[h * STRIDE + jbase]);
        __hip_bfloat162 wp = *reinterpret_cast<const __hip_bfloat162*>(&sW2h[h * C + c2]);
        float wx = __bfloat162float(wp.x), wy = __bfloat162float(wp.y);
        a0 = fmaf(hv.x, wx, a0); a1 = fmaf(hv.y, wx, a1);
        a2 = fmaf(hv.z, wx, a2); a3 = fmaf(hv.w, wx, a3);
        c0 = fmaf(hv.x, wy, c0); c1 = fmaf(hv.y, wy, c1);
        c2a = fmaf(hv.z, wy, c2a); c3 = fmaf(hv.w, wy, c3);
      }
      if (jbase + 0 < jt) { m0 = fmaxf(m0, a0); m1 = fmaxf(m1, c0); }
      if (jbase + 1 < jt) { m0 = fmaxf(m0, a1); m1 = fmaxf(m1, c1); }
      if (jbase + 2 < jt) { m0 = fmaxf(m0, a2); m1 = fmaxf(m1, c2a); }
      if (jbase + 3 < jt) { m0 = fmaxf(m0, a3); m1 = fmaxf(m1, c3); }
    }
    __syncthreads();
    sRed[sgi * C + c2]     = m0;
    sRed[sgi * C + c2 + 1] = m1;
    __syncthreads();
    if (tid < TPS) {
      int c = 2 * tid;
      float M0 = sRed[c], M1 = sRed[c + 1];
      #pragma unroll
      for (int s2 = 1; s2 < SG; ++s2) {
        M0 = fmaxf(M0, sRed[s2 * C + c]);
        M1 = fmaxf(M1, sRed[s2 * C + c + 1]);
      }
      float o0 = nn > 0 ? M0 + b2v[c]     : 0.f;
      float o1 = nn > 0 ? M1 + b2v[c + 1] : 0.f;
      float* orow = outb + (size_t)i * C;
      orow[c] = o0; orow[c + 1] = o1;
    }
    __syncthreads();
  }
}

template<int N, int H, int C, int QB>
__global__ __launch_bounds__(256) void sa_kernel(
    const float* __restrict__ src, const float* __restrict__ g,
    const float* __restrict__ qpos, const float* __restrict__ W2,
    const float* __restrict__ b1v, const float* __restrict__ W1p,
    const float* __restrict__ b2v, float r2, int M, float* __restrict__ out) {
  __shared__ __align__(16) char smem[sa_smem_bytes<N, H, C, 256>()];
  const int b = blockIdx.y;
  sa_body<N, H, C, QB, 256>(src + (size_t)b * N * 3, g + (size_t)b * N * H,
                            qpos + (size_t)b * M * 3, W2, b1v, W1p, b2v, r2, M,
                            out + (size_t)b * M * C, blockIdx.x, smem);
}

// ------- fused: blocks 0-7 run FPS (next layer's sampling), rest run SA (this layer) -------
template<int NF, int MF, int NPTF, int NS, int HS, int CS, int QB, int SAB>
__global__ __launch_bounds__(512, 2) void fused_kernel(
    const float* __restrict__ fsrc, float* __restrict__ fdst,
    const float* __restrict__ src, const float* __restrict__ g,
    const float* __restrict__ qpos, const float* __restrict__ W2,
    const float* __restrict__ b1v, const float* __restrict__ W1p,
    const float* __restrict__ b2v, float r2, int M, float* __restrict__ out) {
  constexpr int FPS_BYTES = 16 * NF + 2 * 8 * 16;
  constexpr int SA_BYTES  = sa_smem_bytes<NS, HS, CS, 512>();
  constexpr int SMEM = FPS_BYTES > SA_BYTES ? FPS_BYTES : SA_BYTES;
  __shared__ __align__(16) char smem[SMEM];
  if (blockIdx.x < 8) {
    __builtin_amdgcn_s_setprio(3);  // FPS is the latency-critical serial chain
    fps_body<NF, MF, NPTF, 512>(fsrc + (size_t)blockIdx.x * NF * 3,
                                fdst + (size_t)blockIdx.x * MF * 3, smem);
    return;
  }
  const int bi = blockIdx.x - 8;
  const int qt = bi % SAB;
  const int b  = bi / SAB;
  sa_body<NS, HS, CS, QB, 512>(src + (size_t)b * NS * 3, g + (size_t)b * NS * HS,
                               qpos + (size_t)b * M * 3, W2, b1v, W1p, b2v, r2, M,
                               out + (size_t)b * M * CS, qt, smem);
}

// ---------------- tail: copy p3 and synthesize batch ids into d_out ----------------
__global__ void tail_kernel(const float* __restrict__ p3, float* __restrict__ d_out) {
  int i = blockIdx.x * 256 + threadIdx.x;
  if (i < 8 * 512 * 3) d_out[524288 + i] = p3[i];
  if (i < 8 * 512)     d_out[536576 + i] = (float)(i >> 9);
}

extern "C" void kernel_launch(void* const* d_in, const int* in_sizes, int n_in,
                              void* d_out, int out_size, void* d_ws, size_t ws_size,
                              hipStream_t stream) {
  (void)in_sizes; (void)n_in; (void)out_size; (void)ws_size;
  const float* pos = (const float*)d_in[0];
  const float* w11 = (const float*)d_in[2];
  const float* b11 = (const float*)d_in[3];
  const float* w12 = (const float*)d_in[4];
  const float* b12 = (const float*)d_in[5];
  const float* w21 = (const float*)d_in[6];
  const float* b21 = (const float*)d_in[7];
  const float* w22 = (const float*)d_in[8];
  const float* b22 = (const float*)d_in[9];
  const float* w31 = (const float*)d_in[10];
  const float* b31 = (const float*)d_in[11];
  const float* w32 = (const float*)d_in[12];
  const float* b32 = (const float*)d_in[13];

  float* ws = (float*)d_ws;
  float* p1 = ws; ws += 8 * 2048 * 3;
  float* p2 = ws; ws += 8 * 512 * 3;
  float* p3 = ws; ws += 8 * 512 * 3;
  float* g1 = ws; ws += 8 * 4096 * 32;
  float* x1 = ws; ws += 8 * 2048 * 32;
  float* g2 = ws; ws += 8 * 2048 * 64;
  float* x2 = ws; ws += 8 * 512 * 64;
  float* g3 = ws; ws += 8 * 512 * 128;
  float* x3 = (float*)d_out;

  // layer 1: g1 (tiny, independent), then FPS1 (the long serial chain)
  g_kernel<3, 32><<<dim3(8 * 4096 * 32 / 256), dim3(256), 0, stream>>>(pos, pos, w11, g1, 8 * 4096);
  fps_kernel<4096, 2048, 8><<<dim3(8), dim3(512), 0, stream>>>(pos, p1);

  // fused A: fps2 (p1->p2) overlapped with sa1 (pos,g1,p1 -> x1); SAB = 2048/8 = 256
  fused_kernel<2048, 512, 4, 4096, 32, 32, 8, 256><<<dim3(8 + 8 * 256), dim3(512), 0, stream>>>(
      p1, p2, pos, g1, p1, w12, b11, w11 + 3 * 32, b12, 0.04f, 2048, x1);

  g_kernel<32, 64><<<dim3(8 * 2048 * 64 / 256), dim3(256), 0, stream>>>(x1, p1, w21, g2, 8 * 2048);

  // fused B: fps3 (p2->p3) overlapped with sa2 (p1,g2,p2 -> x2); SAB = 512/8 = 64
  fused_kernel<512, 512, 1, 2048, 64, 64, 8, 64><<<dim3(8 + 8 * 64), dim3(512), 0, stream>>>(
      p2, p3, p1, g2, p2, w22, b21, w21 + 32 * 64, b22, 0.16f, 512, x2);

  g_kernel<64, 128><<<dim3(8 * 512 * 128 / 256), dim3(256), 0, stream>>>(x2, p2, w31, g3, 8 * 512);

  sa_kernel<512, 128, 128, 8><<<dim3(64, 8), dim3(256), 0, stream>>>(
      p2, g3, p3, w32, b31, w31 + 64 * 128, b32, 1.0f, 512, x3);

  tail_kernel<<<dim3(48), dim3(256), 0, stream>>>(p3, (float*)d_out);
}